// Round 1
// 1593.489 us; speedup vs baseline: 1.3388x; 1.3388x over previous
//
#include <hip/hip_runtime.h>
#include <hip/hip_fp16.h>
#include <math.h>

// Problem constants (fixed shapes from the reference)
#define BB 32
#define SS 256
#define EE 300
#define EP 304          // E padded to multiple of 16
#define HH 256
#define TT 19           // NUM_TAGS + START + STOP
#define START_TAG 17
#define STOP_TAG 18
#define BS 8192         // B*S
#define GIN_PER_DIR (8192*1024)

// Persistent register-resident weight count per thread (uint4 units).
// 40 uint4 = 160 VGPR persistent; budget is 256 VGPR at __launch_bounds__(512,2).
#define P_REG 40

__device__ __forceinline__ float sigm(float x){ return 1.0f/(1.0f+expf(-x)); }

#ifdef __has_builtin
#if __has_builtin(__builtin_amdgcn_fdot2)
#define HAVE_FDOT2 1
#endif
#endif

// v_dot2_f32_f16: acc += lo(w)*lo(h) + hi(w)*hi(h), f32 accumulate
__device__ __forceinline__ float dot2(unsigned int w, unsigned int h, float acc){
#ifdef HAVE_FDOT2
  typedef _Float16 h2_t __attribute__((ext_vector_type(2)));
  return __builtin_amdgcn_fdot2(__builtin_bit_cast(h2_t, w),
                                __builtin_bit_cast(h2_t, h), acc, false);
#else
  float r;
  asm("v_dot2_f32_f16 %0, %1, %2, %3" : "=v"(r) : "v"(w), "v"(h), "v"(acc));
  return r;
#endif
}

// RNE pack of two f32 h-values into a half2 dword
__device__ __forceinline__ unsigned int pack_h2(float a, float b){
  unsigned int lo = __half_as_ushort(__float2half(a));
  unsigned int hi = __half_as_ushort(__float2half(b));
  return (hi << 16) | lo;
}

// 16 dot2 = 32 MACs: one k-chunk of 8 (uint4 hu = 8 packed fp16 h) x 4 gates
__device__ __forceinline__ void mac4(uint4 w0, uint4 w1, uint4 w2, uint4 w3, uint4 hu,
                                     float& ai, float& af, float& ag, float& ao){
  ai = dot2(w0.x, hu.x, ai); ai = dot2(w0.y, hu.y, ai); ai = dot2(w0.z, hu.z, ai); ai = dot2(w0.w, hu.w, ai);
  af = dot2(w1.x, hu.x, af); af = dot2(w1.y, hu.y, af); af = dot2(w1.z, hu.z, af); af = dot2(w1.w, hu.w, af);
  ag = dot2(w2.x, hu.x, ag); ag = dot2(w2.y, hu.y, ag); ag = dot2(w2.z, hu.z, ag); ag = dot2(w2.w, hu.w, ag);
  ao = dot2(w3.x, hu.x, ao); ao = dot2(w3.y, hu.y, ao); ao = dot2(w3.z, hu.z, ao); ao = dot2(w3.w, hu.w, ao);
}

// ---------------- ws layout (float offsets) ----------------
// x_pad : [BS][304]            off 0          size 2490368
// WT    : [304][2048]          off 2490368    size 622592   (transposed+padded, cols permuted to (j*4+g))
// bias2 : [2048]               off 3112960    size 2048
// W16   : fp16 Whh packed      off 3115008    size 262144 floats used (1 MB)
//         uint4 index: (d*64 + q)*512 + tid ; q = u*4+g (u=0..15 k-chunk, g=gate)
//         tid = kpart*256+urow (kpart 2-way) ; dword j holds k = kpart*128 + u*8 + j*2 (+1 hi)
// gin   : [2][BS][1024]        off 3639296    size 16777216 (preacts, interleaved row j*4+g)
// hseq  : [BS][512]            off 20416512   size 4194304
// emit  : [BS][19]             off 24610816   size 155648
// ptr   : [BS][19] (int)       off 24766464   size 155648
// nll   : [32]                 off 24922112

// -------- embed gather + mask, pad E to 304 with zeros --------
__global__ void k_embed(const int* __restrict__ wi, const int* __restrict__ msk,
                        const float* __restrict__ emb, float* __restrict__ x){
  int id = blockIdx.x*256 + threadIdx.x;        // BS*76 float4 slots
  if (id >= BS*76) return;
  int row = id / 76, q = id - row*76;
  float4 v = make_float4(0.f,0.f,0.f,0.f);
  if (q < 75){                                   // 75*4 = 300 real elements
    const float4* e4 = (const float4*)emb;       // emb rows are 1200B = 16B aligned
    v = e4[(size_t)wi[row]*75 + q];
    float m = (float)msk[row];
    v.x*=m; v.y*=m; v.z*=m; v.w*=m;
  }
  ((float4*)x)[(size_t)row*76 + q] = v;
}

// -------- transpose Wih into WT[304][2048] with PERMUTED columns, build bias --------
// column n: dd = n>>10 (dir), r = n&1023, j = r>>2 (h-row), g = r&3 (gate)
__global__ void k_prep_wt(const float* __restrict__ Wih_f, const float* __restrict__ Wih_b,
                          const float* __restrict__ bih_f, const float* __restrict__ bhh_f,
                          const float* __restrict__ bih_b, const float* __restrict__ bhh_b,
                          float* __restrict__ WT, float* __restrict__ bias){
  int id = blockIdx.x*256 + threadIdx.x;
  if (id < 304*2048){
    int k = id >> 11, n = id & 2047;
    int dd = n >> 10, r = n & 1023, j = r >> 2, g = r & 3;
    int orow = g*256 + j;
    float v = 0.f;
    if (k < 300) v = dd ? Wih_b[orow*300 + k] : Wih_f[orow*300 + k];
    WT[id] = v;
  } else {
    int n = id - 304*2048;
    if (n < 2048){
      int dd = n >> 10, r = n & 1023, j = r >> 2, g = r & 3;
      int orow = g*256 + j;
      bias[n] = dd ? (bih_b[orow] + bhh_b[orow]) : (bih_f[orow] + bhh_f[orow]);
    }
  }
}

// -------- pack Whh to fp16 for k_lstm v7 (layout in ws map) --------
__global__ void k_prep_whh16(const float* __restrict__ Whh_f, const float* __restrict__ Whh_b,
                             unsigned int* __restrict__ out){
  int id = blockIdx.x*256 + threadIdx.x;        // 262144 uints
  int j   = id & 3;
  int u4  = id >> 2;                             // uint4 index
  int tid = u4 & 511;
  int q   = (u4 >> 9) & 63;
  int d   = u4 >> 15;
  int kpart = tid >> 8, urow = tid & 255;
  int u = q >> 2, g = q & 3;
  int k = kpart*128 + u*8 + j*2;
  const float* W = d ? Whh_b : Whh_f;
  float w0 = W[(size_t)(g*256 + urow)*256 + k];
  float w1 = W[(size_t)(g*256 + urow)*256 + k + 1];
  unsigned u0 = __half_as_ushort(__float2half(w0));
  unsigned u1 = __half_as_ushort(__float2half(w1));
  out[id] = (u1 << 16) | u0;
}

// -------- input-gate GEMM: gin[dd][row][r] = x @ WT[:,n] + bias[n] --------
__global__ __launch_bounds__(256) void k_gemm(const float* __restrict__ x,
      const float* __restrict__ WT, const float* __restrict__ bias,
      float* __restrict__ gin){
  __shared__ float As[16][65];
  __shared__ float Bs[16][64];
  int tid = threadIdx.x;
  int tx = tid & 15, ty = tid >> 4;
  int n0 = blockIdx.x * 64, m0 = blockIdx.y * 64;
  float acc[4][4] = {};
  for (int kt = 0; kt < 19; ++kt){
    int k0 = kt*16;
    #pragma unroll
    for (int i = 0; i < 4; ++i){
      int idx = tid + i*256;
      int ak = idx & 15, am = idx >> 4;
      As[ak][am] = x[(size_t)(m0+am)*304 + (k0+ak)];
      int bn = idx & 63, bk = idx >> 6;
      Bs[bk][bn] = WT[(size_t)(k0+bk)*2048 + (n0+bn)];
    }
    __syncthreads();
    #pragma unroll
    for (int k = 0; k < 16; ++k){
      float a0 = As[k][ty*4+0], a1 = As[k][ty*4+1], a2 = As[k][ty*4+2], a3 = As[k][ty*4+3];
      float b0 = Bs[k][tx*4+0], b1 = Bs[k][tx*4+1], b2 = Bs[k][tx*4+2], b3 = Bs[k][tx*4+3];
      acc[0][0]+=a0*b0; acc[0][1]+=a0*b1; acc[0][2]+=a0*b2; acc[0][3]+=a0*b3;
      acc[1][0]+=a1*b0; acc[1][1]+=a1*b1; acc[1][2]+=a1*b2; acc[1][3]+=a1*b3;
      acc[2][0]+=a2*b0; acc[2][1]+=a2*b1; acc[2][2]+=a2*b2; acc[2][3]+=a2*b3;
      acc[3][0]+=a3*b0; acc[3][1]+=a3*b1; acc[3][2]+=a3*b2; acc[3][3]+=a3*b3;
    }
    __syncthreads();
  }
  #pragma unroll
  for (int i = 0; i < 4; ++i){
    int m = m0 + ty*4 + i;
    #pragma unroll
    for (int j = 0; j < 4; ++j){
      int n = n0 + tx*4 + j;
      int dd = n >> 10, r = n & 1023;
      gin[(size_t)dd*GIN_PER_DIR + (size_t)m*1024 + r] = acc[i][j] + bias[n];
    }
  }
}

// -------- BiLSTM recurrence v7: register-resident fp16 weights + v_dot2 --------
// 512 threads (kpart 2-way x 256 h-rows), __launch_bounds__(512,2) -> 256 VGPR budget.
// Each thread: 4 gate partials of h-row urow over k in [kpart*128, +128) = 64 uint4
// weights/step. P_REG=40 uint4 (160 VGPR) held persistent across all 256 steps;
// only 24 uint4 (192 KB/block/step, vs 512 KB before) streamed from L2.
// MACs via v_dot2_f32_f16 (fp16 pair x pair, f32 acc): 16 dot2 per k-chunk of 8
// replaces ~16 cvt + 8 fma. h kept in LDS as packed half2 (RNE), repacked each step.
__global__ __launch_bounds__(512, 2) void k_lstm(const float* __restrict__ gin,
                 const uint4* __restrict__ W16, float* __restrict__ hseq){
  int tid = threadIdx.x;
  int b = blockIdx.x & 31, d = blockIdx.x >> 5;
  int kpart = tid >> 8;                              // 0..1
  const uint4* wq = W16 + (size_t)d*64*512 + tid;    // + q*512 per q
  const float* gb = gin + (size_t)d*GIN_PER_DIR + (size_t)b*SS*1024;

  __shared__ uint4  hs16q[32];     // 128 half2 dwords = h[0..255] packed fp16
  __shared__ float4 gl4[512];      // gate partial exchange

  if (tid < 32) hs16q[tid] = make_uint4(0u,0u,0u,0u);
  float c = 0.f;

  uint4 wreg[P_REG];
  #pragma unroll
  for (int i = 0; i < P_REG; ++i) wreg[i] = wq[i*512];
  __syncthreads();

  for (int s = 0; s < SS; ++s){
    int t = d ? (SS-1-s) : s;
    float4 gv = make_float4(0.f,0.f,0.f,0.f);
    if (tid < 256) gv = ((const float4*)(gb + (size_t)t*1024))[tid];  // prefetch preacts

    float ai = 0.f, af = 0.f, ag = 0.f, ao = 0.f;
    // persistent chunks: u = 0..9  (q = u*4+g < P_REG)
    #pragma unroll
    for (int u = 0; u < 10; ++u){
      uint4 hu = hs16q[kpart*16 + u];                // wave-uniform LDS broadcast
      mac4(wreg[u*4+0], wreg[u*4+1], wreg[u*4+2], wreg[u*4+3], hu, ai, af, ag, ao);
    }
    // streamed chunks: u = 10..15 (24 coalesced dwordx4 loads, L2-resident)
    #pragma unroll
    for (int u = 10; u < 16; ++u){
      uint4 hu = hs16q[kpart*16 + u];
      uint4 w0 = wq[(u*4+0)*512];
      uint4 w1 = wq[(u*4+1)*512];
      uint4 w2 = wq[(u*4+2)*512];
      uint4 w3 = wq[(u*4+3)*512];
      mac4(w0, w1, w2, w3, hu, ai, af, ag, ao);
    }
    gl4[tid] = make_float4(ai, af, ag, ao);
    __syncthreads();
    if (tid < 256){
      float4 p0 = gl4[tid], p1 = gl4[256+tid];
      float iv = sigm (p0.x + p1.x + gv.x);
      float fv = sigm (p0.y + p1.y + gv.y);
      float gg = tanhf(p0.z + p1.z + gv.z);
      float ov = sigm (p0.w + p1.w + gv.w);
      c = fv*c + iv*gg;
      float hv = ov*tanhf(c);
      hseq[((size_t)(b*SS + t))*512 + d*256 + tid] = hv;
      float hp = __shfl_xor(hv, 1);                  // partner h within wave
      if (!(tid & 1))
        ((unsigned int*)hs16q)[tid >> 1] = pack_h2(hv, hp);
    }
    __syncthreads();
  }
}

// -------- tag logits: emit[row][t] = hseq[row] . W_tag[t] + b_tag[t] --------
__global__ void k_emit(const float* __restrict__ hseq, const float* __restrict__ Wtag,
                       const float* __restrict__ btag, float* __restrict__ emit){
  int id = blockIdx.x*256 + threadIdx.x;
  if (id >= BS*TT) return;
  int row = id / TT, tg = id - row*TT;
  const float4* hp = (const float4*)(hseq + (size_t)row*512);
  const float4* wp = (const float4*)(Wtag + (size_t)tg*512);
  float acc = btag[tg];
  #pragma unroll 8
  for (int k = 0; k < 128; ++k){
    float4 h = hp[k], w = wp[k];
    acc += h.x*w.x + h.y*w.y + h.z*w.z + h.w*w.w;
  }
  emit[id] = acc;
}

// -------- fused CRF NLL + Viterbi: blocks 0..31 CRF(b), 32..63 Viterbi(b-32) --------
__global__ void k_crfvit(const float* __restrict__ emit, const int* __restrict__ msk,
                         const int* __restrict__ lab, const float* __restrict__ trans,
                         float* __restrict__ nll, int* __restrict__ ptr,
                         float* __restrict__ out){
  int tid = threadIdx.x;
  __shared__ float tr[361];
  __shared__ float al[19];
  __shared__ int tg[256];
  for (int i = tid; i < 361; i += 64) tr[i] = trans[i];

  if (blockIdx.x < 32){
    // ---- CRF forward (NLL) ----
    int b = blockIdx.x;
    const float* eb = emit + (size_t)b*SS*TT;
    const int* mb = msk + b*SS;
    const int* lb = lab + b*SS;
    __syncthreads();
    float gp = 0.f; int ln = 0;
    for (int t = tid; t < SS; t += 64){
      int m = mb[t];
      ln += m;
      if (m){
        int l = lb[t];
        int p = t ? lb[t-1] : START_TAG;
        gp += tr[p*19 + l] + eb[t*19 + l];
      }
    }
    for (int off = 32; off; off >>= 1){ gp += __shfl_down(gp, off); ln += __shfl_down(ln, off); }
    float gold = 0.f;
    if (tid == 0){
      int lt = lb[ln - 1];
      gold = gp + tr[lt*19 + STOP_TAG];
    }
    if (tid < 19) al[tid] = eb[tid] + tr[START_TAG*19 + tid];
    __syncthreads();
    for (int t = 1; t < SS; ++t){
      int m = mb[t];
      float nv = 0.f;
      if (tid < 19){
        float mx = -1e30f;
        for (int p = 0; p < 19; ++p){ float v = al[p] + tr[p*19 + tid]; mx = fmaxf(mx, v); }
        float sum = 0.f;
        for (int p = 0; p < 19; ++p) sum += expf(al[p] + tr[p*19 + tid] - mx);
        nv = mx + logf(sum) + eb[t*19 + tid];
      }
      __syncthreads();
      if (tid < 19 && m) al[tid] = nv;
      __syncthreads();
    }
    if (tid == 0){
      float mx = -1e30f;
      for (int c2 = 0; c2 < 19; ++c2) mx = fmaxf(mx, al[c2] + tr[c2*19 + STOP_TAG]);
      float sum = 0.f;
      for (int c2 = 0; c2 < 19; ++c2) sum += expf(al[c2] + tr[c2*19 + STOP_TAG] - mx);
      nll[b] = (mx + logf(sum)) - gold;
    }
  } else {
    // ---- Viterbi decode ----
    int b = blockIdx.x - 32;
    const float* eb = emit + (size_t)b*SS*TT;
    const int* mb = msk + b*SS;
    int* pb = ptr + (size_t)b*SS*TT;
    if (tid < 19) al[tid] = eb[tid] + tr[START_TAG*19 + tid];   // al doubles as delta
    __syncthreads();
    for (int t = 1; t < SS; ++t){
      int m = mb[t];
      float best = -1e30f; int bp = 0;
      if (tid < 19){
        for (int p = 0; p < 19; ++p){
          float v = al[p] + tr[p*19 + tid];
          if (v > best){ best = v; bp = p; }       // strict > == first-max (jnp.argmax)
        }
      }
      __syncthreads();
      if (tid < 19){
        if (m){ al[tid] = best + eb[t*19 + tid]; pb[t*19 + tid] = bp; }
        else  { pb[t*19 + tid] = tid; }            // identity pass-through when padded
      }
      __syncthreads();
    }
    if (tid == 0){
      float bv = -1e30f; int bl = 0;
      for (int c2 = 0; c2 < 19; ++c2){
        float v = al[c2] + tr[c2*19 + STOP_TAG];
        if (v > bv){ bv = v; bl = c2; }
      }
      tg[SS-1] = bl;
      for (int t = SS-1; t > 0; --t) tg[t-1] = pb[t*19 + tg[t]];
    }
    __syncthreads();
    for (int t = tid; t < SS; t += 64)
      out[1 + b*SS + t] = (float)(tg[t] * mb[t]);
  }
}

// -------- final loss reduce: d_out[0] = sum(nll)/B --------
__global__ void k_final(const float* __restrict__ nll, float* __restrict__ out){
  int tid = threadIdx.x;
  float v = (tid < 32) ? nll[tid] : 0.f;
  for (int off = 32; off; off >>= 1) v += __shfl_down(v, off);
  if (tid == 0) out[0] = v * (1.0f/32.0f);
}

extern "C" void kernel_launch(void* const* d_in, const int* in_sizes, int n_in,
                              void* d_out, int out_size, void* d_ws, size_t ws_size,
                              hipStream_t stream){
  const int*   wi    = (const int*)d_in[0];
  const int*   msk   = (const int*)d_in[1];
  const int*   lab   = (const int*)d_in[2];
  // d_in[3] labels_token, d_in[4] data_type: unused (data_type==1 branch)
  const float* emb   = (const float*)d_in[5];
  const float* Wih_f = (const float*)d_in[6];
  const float* Whh_f = (const float*)d_in[7];
  const float* bih_f = (const float*)d_in[8];
  const float* bhh_f = (const float*)d_in[9];
  const float* Wih_b = (const float*)d_in[10];
  const float* Whh_b = (const float*)d_in[11];
  const float* bih_b = (const float*)d_in[12];
  const float* bhh_b = (const float*)d_in[13];
  const float* Wtag  = (const float*)d_in[14];
  const float* btag  = (const float*)d_in[15];
  const float* trans = (const float*)d_in[16];

  float* ws   = (float*)d_ws;
  float* x    = ws;
  float* WT   = ws + 2490368;
  float* bias = ws + 3112960;
  unsigned int* W16u = (unsigned int*)(ws + 3115008);
  uint4* W16  = (uint4*)W16u;
  float* gin  = ws + 3639296;
  float* hseq = ws + 20416512;
  float* emit = ws + 24610816;
  int*   ptr  = (int*)(ws + 24766464);
  float* nll  = ws + 24922112;
  float* out  = (float*)d_out;

  hipLaunchKernelGGL(k_embed,      dim3(2432),    dim3(256),  0, stream, wi, msk, emb, x);
  hipLaunchKernelGGL(k_prep_wt,    dim3(2440),    dim3(256),  0, stream,
                     Wih_f, Wih_b, bih_f, bhh_f, bih_b, bhh_b, WT, bias);
  hipLaunchKernelGGL(k_prep_whh16, dim3(1024),    dim3(256),  0, stream, Whh_f, Whh_b, W16u);
  hipLaunchKernelGGL(k_gemm,       dim3(32,128),  dim3(256),  0, stream, x, WT, bias, gin);
  hipLaunchKernelGGL(k_lstm,       dim3(64),      dim3(512),  0, stream, gin, W16, hseq);
  hipLaunchKernelGGL(k_emit,       dim3(608),     dim3(256),  0, stream, hseq, Wtag, btag, emit);
  hipLaunchKernelGGL(k_crfvit,     dim3(64),      dim3(64),   0, stream, emit, msk, lab, trans,
                     nll, ptr, out);
  hipLaunchKernelGGL(k_final,      dim3(1),       dim3(64),   0, stream, nll, out);
}

// Round 2
// 1105.095 us; speedup vs baseline: 1.9305x; 1.4419x over previous
//
#include <hip/hip_runtime.h>
#include <hip/hip_fp16.h>
#include <math.h>

// Problem constants (fixed shapes from the reference)
#define BB 32
#define SS 256
#define EE 300
#define EP 304          // E padded to multiple of 16
#define HH 256
#define TT 19           // NUM_TAGS + START + STOP
#define START_TAG 17
#define STOP_TAG 18
#define BS 8192         // B*S
#define GIN_PER_DIR (8192*1024)

// k_lstm v8 weight residency split (per thread, of 16 u-chunks x 4 gates):
//   RCH u-chunks in registers (volatile-asm pinned), 16-RCH u-chunks in LDS.
#define RCH 12                       // 48 uint4 = 192 VGPR persistent
#define LDS_WCHUNK (16 - RCH)        // 4 chunks -> 16 slots x 512 uint4 = 128 KB
#define K_LSTM_LDS_BYTES ((8192 + 32 + 256) * 16)   // wlds + hsq + glh = 135680 B

__device__ __forceinline__ float sigm(float x){ return 1.0f/(1.0f+expf(-x)); }

#ifdef __has_builtin
#if __has_builtin(__builtin_amdgcn_fdot2)
#define HAVE_FDOT2 1
#endif
#endif

// v_dot2_f32_f16: acc += lo(w)*lo(h) + hi(w)*hi(h), f32 accumulate
__device__ __forceinline__ float dot2(unsigned int w, unsigned int h, float acc){
#ifdef HAVE_FDOT2
  typedef _Float16 h2_t __attribute__((ext_vector_type(2)));
  return __builtin_amdgcn_fdot2(__builtin_bit_cast(h2_t, w),
                                __builtin_bit_cast(h2_t, h), acc, false);
#else
  float r;
  asm("v_dot2_f32_f16 %0, %1, %2, %3" : "=v"(r) : "v"(w), "v"(h), "v"(acc));
  return r;
#endif
}

// volatile-asm 16B load: cannot be duplicated/rematerialized by the compiler,
// so the result MUST stay register-resident across the step loop.
__device__ __forceinline__ uint4 vload_u4(const uint4* p){
  uint4 r;
  asm volatile("global_load_dwordx4 %0, %1, off"
               : "=&v"(r) : "v"(p) : "memory");
  return r;
}

// RNE pack of two f32 h-values into a half2 dword
__device__ __forceinline__ unsigned int pack_h2(float a, float b){
  unsigned int lo = __half_as_ushort(__float2half(a));
  unsigned int hi = __half_as_ushort(__float2half(b));
  return (hi << 16) | lo;
}

// 16 dot2 = 32 MACs: one k-chunk of 8 (uint4 hu = 8 packed fp16 h) x 4 gates
__device__ __forceinline__ void mac4(uint4 w0, uint4 w1, uint4 w2, uint4 w3, uint4 hu,
                                     float& ai, float& af, float& ag, float& ao){
  ai = dot2(w0.x, hu.x, ai); ai = dot2(w0.y, hu.y, ai); ai = dot2(w0.z, hu.z, ai); ai = dot2(w0.w, hu.w, ai);
  af = dot2(w1.x, hu.x, af); af = dot2(w1.y, hu.y, af); af = dot2(w1.z, hu.z, af); af = dot2(w1.w, hu.w, af);
  ag = dot2(w2.x, hu.x, ag); ag = dot2(w2.y, hu.y, ag); ag = dot2(w2.z, hu.z, ag); ag = dot2(w2.w, hu.w, ag);
  ao = dot2(w3.x, hu.x, ao); ao = dot2(w3.y, hu.y, ao); ao = dot2(w3.z, hu.z, ao); ao = dot2(w3.w, hu.w, ao);
}

// ---------------- ws layout (float offsets) ----------------
// x_pad : [BS][304]            off 0          size 2490368
// WT    : [304][2048]          off 2490368    size 622592   (transposed+padded, cols permuted to (j*4+g))
// bias2 : [2048]               off 3112960    size 2048
// W16   : fp16 Whh packed      off 3115008    size 262144 floats used (1 MB)
//         uint4 index: (d*64 + q)*512 + tid ; q = u*4+g (u=0..15 k-chunk, g=gate)
//         tid = kpart*256+urow (kpart 2-way) ; dword j holds k = kpart*128 + u*8 + j*2 (+1 hi)
// gin   : [2][BS][1024]        off 3639296    size 16777216 (preacts, interleaved row j*4+g)
// hseq  : [BS][512]            off 20416512   size 4194304
// emit  : [BS][19]             off 24610816   size 155648
// ptr   : [BS][19] (int)       off 24766464   size 155648
// nll   : [32]                 off 24922112

// -------- embed gather + mask, pad E to 304 with zeros --------
__global__ void k_embed(const int* __restrict__ wi, const int* __restrict__ msk,
                        const float* __restrict__ emb, float* __restrict__ x){
  int id = blockIdx.x*256 + threadIdx.x;        // BS*76 float4 slots
  if (id >= BS*76) return;
  int row = id / 76, q = id - row*76;
  float4 v = make_float4(0.f,0.f,0.f,0.f);
  if (q < 75){                                   // 75*4 = 300 real elements
    const float4* e4 = (const float4*)emb;       // emb rows are 1200B = 16B aligned
    v = e4[(size_t)wi[row]*75 + q];
    float m = (float)msk[row];
    v.x*=m; v.y*=m; v.z*=m; v.w*=m;
  }
  ((float4*)x)[(size_t)row*76 + q] = v;
}

// -------- transpose Wih into WT[304][2048] with PERMUTED columns, build bias --------
// column n: dd = n>>10 (dir), r = n&1023, j = r>>2 (h-row), g = r&3 (gate)
__global__ void k_prep_wt(const float* __restrict__ Wih_f, const float* __restrict__ Wih_b,
                          const float* __restrict__ bih_f, const float* __restrict__ bhh_f,
                          const float* __restrict__ bih_b, const float* __restrict__ bhh_b,
                          float* __restrict__ WT, float* __restrict__ bias){
  int id = blockIdx.x*256 + threadIdx.x;
  if (id < 304*2048){
    int k = id >> 11, n = id & 2047;
    int dd = n >> 10, r = n & 1023, j = r >> 2, g = r & 3;
    int orow = g*256 + j;
    float v = 0.f;
    if (k < 300) v = dd ? Wih_b[orow*300 + k] : Wih_f[orow*300 + k];
    WT[id] = v;
  } else {
    int n = id - 304*2048;
    if (n < 2048){
      int dd = n >> 10, r = n & 1023, j = r >> 2, g = r & 3;
      int orow = g*256 + j;
      bias[n] = dd ? (bih_b[orow] + bhh_b[orow]) : (bih_f[orow] + bhh_f[orow]);
    }
  }
}

// -------- pack Whh to fp16 for k_lstm (layout in ws map) --------
__global__ void k_prep_whh16(const float* __restrict__ Whh_f, const float* __restrict__ Whh_b,
                             unsigned int* __restrict__ out){
  int id = blockIdx.x*256 + threadIdx.x;        // 262144 uints
  int j   = id & 3;
  int u4  = id >> 2;                             // uint4 index
  int tid = u4 & 511;
  int q   = (u4 >> 9) & 63;
  int d   = u4 >> 15;
  int kpart = tid >> 8, urow = tid & 255;
  int u = q >> 2, g = q & 3;
  int k = kpart*128 + u*8 + j*2;
  const float* W = d ? Whh_b : Whh_f;
  float w0 = W[(size_t)(g*256 + urow)*256 + k];
  float w1 = W[(size_t)(g*256 + urow)*256 + k + 1];
  unsigned u0 = __half_as_ushort(__float2half(w0));
  unsigned u1 = __half_as_ushort(__float2half(w1));
  out[id] = (u1 << 16) | u0;
}

// -------- input-gate GEMM: gin[dd][row][r] = x @ WT[:,n] + bias[n] --------
__global__ __launch_bounds__(256) void k_gemm(const float* __restrict__ x,
      const float* __restrict__ WT, const float* __restrict__ bias,
      float* __restrict__ gin){
  __shared__ float As[16][65];
  __shared__ float Bs[16][64];
  int tid = threadIdx.x;
  int tx = tid & 15, ty = tid >> 4;
  int n0 = blockIdx.x * 64, m0 = blockIdx.y * 64;
  float acc[4][4] = {};
  for (int kt = 0; kt < 19; ++kt){
    int k0 = kt*16;
    #pragma unroll
    for (int i = 0; i < 4; ++i){
      int idx = tid + i*256;
      int ak = idx & 15, am = idx >> 4;
      As[ak][am] = x[(size_t)(m0+am)*304 + (k0+ak)];
      int bn = idx & 63, bk = idx >> 6;
      Bs[bk][bn] = WT[(size_t)(k0+bk)*2048 + (n0+bn)];
    }
    __syncthreads();
    #pragma unroll
    for (int k = 0; k < 16; ++k){
      float a0 = As[k][ty*4+0], a1 = As[k][ty*4+1], a2 = As[k][ty*4+2], a3 = As[k][ty*4+3];
      float b0 = Bs[k][tx*4+0], b1 = Bs[k][tx*4+1], b2 = Bs[k][tx*4+2], b3 = Bs[k][tx*4+3];
      acc[0][0]+=a0*b0; acc[0][1]+=a0*b1; acc[0][2]+=a0*b2; acc[0][3]+=a0*b3;
      acc[1][0]+=a1*b0; acc[1][1]+=a1*b1; acc[1][2]+=a1*b2; acc[1][3]+=a1*b3;
      acc[2][0]+=a2*b0; acc[2][1]+=a2*b1; acc[2][2]+=a2*b2; acc[2][3]+=a2*b3;
      acc[3][0]+=a3*b0; acc[3][1]+=a3*b1; acc[3][2]+=a3*b2; acc[3][3]+=a3*b3;
    }
    __syncthreads();
  }
  #pragma unroll
  for (int i = 0; i < 4; ++i){
    int m = m0 + ty*4 + i;
    #pragma unroll
    for (int j = 0; j < 4; ++j){
      int n = n0 + tx*4 + j;
      int dd = n >> 10, r = n & 1023;
      gin[(size_t)dd*GIN_PER_DIR + (size_t)m*1024 + r] = acc[i][j] + bias[n];
    }
  }
}

// -------- BiLSTM recurrence v8: fully-resident weights (VGPR + LDS), zero L2 stream --------
// 512 threads (kpart 2-way x 256 h-rows). Whh for this (d) = 512 KB fp16:
//   - 12 u-chunks/thread (48 uint4 = 192 VGPR) pinned in registers via volatile-asm
//     loads (compiler cannot rematerialize/sink them -> forced residency).
//   - 4 u-chunks block-wide (128 KB) staged once into LDS, streamed at 307 GB/s/CU.
// Steady-state global traffic: gin preacts only (4 KB/step). MACs via v_dot2_f32_f16.
// Cross-kpart reduce: only kpart=1 writes partials to LDS (4 KB); kpart=0 combines
// with its register partials and runs the elementwise epilogue.
__global__ __launch_bounds__(512, 2) void k_lstm(const float* __restrict__ gin,
                 const uint4* __restrict__ W16, float* __restrict__ hseq){
  extern __shared__ uint4 smem[];
  uint4*  wlds = smem;                       // [16 slots][512] = 8192 uint4 (128 KB)
  uint4*  hsq  = smem + 8192;                // 32 uint4: h packed fp16 (512 B)
  float4* glh  = (float4*)(smem + 8224);     // 256 float4: kpart=1 partials (4 KB)

  int tid = threadIdx.x;
  int b = blockIdx.x & 31, d = blockIdx.x >> 5;
  int kpart = tid >> 8;                              // 0..1
  const uint4* wq = W16 + (size_t)d*64*512 + tid;    // + q*512 per q
  const float* gb = gin + (size_t)d*GIN_PER_DIR + (size_t)b*SS*1024;

  // ---- stage LDS weight chunks (u = RCH..15 -> q = 48..63), once ----
  #pragma unroll
  for (int q = 4*RCH; q < 64; ++q)
    wlds[(q - 4*RCH)*512 + tid] = wq[(size_t)q*512];

  if (tid < 32) hsq[tid] = make_uint4(0u,0u,0u,0u);

  // ---- pin register weight chunks (q = 0..47) via volatile asm ----
  uint4 wr[4*RCH];
  #pragma unroll
  for (int q = 0; q < 4*RCH; ++q) wr[q] = vload_u4(wq + (size_t)q*512);
  asm volatile("s_waitcnt vmcnt(0)" ::: "memory");
  __builtin_amdgcn_sched_barrier(0);

  float c = 0.f;
  __syncthreads();

  const uint4* wl = wlds + tid;
  for (int s = 0; s < SS; ++s){
    int t = d ? (SS-1-s) : s;
    float4 gv = make_float4(0.f,0.f,0.f,0.f);
    if (tid < 256) gv = ((const float4*)(gb + (size_t)t*1024))[tid];  // prefetch preacts

    float ai = 0.f, af = 0.f, ag = 0.f, ao = 0.f;
    // register-resident chunks
    #pragma unroll
    for (int u = 0; u < RCH; ++u){
      uint4 hu = hsq[kpart*16 + u];                  // wave-uniform LDS broadcast
      mac4(wr[u*4+0], wr[u*4+1], wr[u*4+2], wr[u*4+3], hu, ai, af, ag, ao);
    }
    // LDS-resident chunks
    #pragma unroll
    for (int uu = 0; uu < LDS_WCHUNK; ++uu){
      uint4 hu = hsq[kpart*16 + RCH + uu];
      uint4 w0 = wl[(uu*4+0)*512];
      uint4 w1 = wl[(uu*4+1)*512];
      uint4 w2 = wl[(uu*4+2)*512];
      uint4 w3 = wl[(uu*4+3)*512];
      mac4(w0, w1, w2, w3, hu, ai, af, ag, ao);
    }
    if (kpart) glh[tid & 255] = make_float4(ai, af, ag, ao);
    __syncthreads();
    if (tid < 256){
      float4 p1 = glh[tid];
      float iv = sigm (ai + p1.x + gv.x);
      float fv = sigm (af + p1.y + gv.y);
      float gg = tanhf(ag + p1.z + gv.z);
      float ov = sigm (ao + p1.w + gv.w);
      c = fv*c + iv*gg;
      float hv = ov*tanhf(c);
      hseq[((size_t)(b*SS + t))*512 + d*256 + tid] = hv;
      float hp = __shfl_xor(hv, 1);                  // partner h within wave
      if (!(tid & 1))
        ((unsigned int*)hsq)[tid >> 1] = pack_h2(hv, hp);
    }
    __syncthreads();
  }
}

// -------- tag logits: emit[row][t] = hseq[row] . W_tag[t] + b_tag[t] --------
__global__ void k_emit(const float* __restrict__ hseq, const float* __restrict__ Wtag,
                       const float* __restrict__ btag, float* __restrict__ emit){
  int id = blockIdx.x*256 + threadIdx.x;
  if (id >= BS*TT) return;
  int row = id / TT, tg = id - row*TT;
  const float4* hp = (const float4*)(hseq + (size_t)row*512);
  const float4* wp = (const float4*)(Wtag + (size_t)tg*512);
  float acc = btag[tg];
  #pragma unroll 8
  for (int k = 0; k < 128; ++k){
    float4 h = hp[k], w = wp[k];
    acc += h.x*w.x + h.y*w.y + h.z*w.z + h.w*w.w;
  }
  emit[id] = acc;
}

// -------- fused CRF NLL + Viterbi: blocks 0..31 CRF(b), 32..63 Viterbi(b-32) --------
__global__ void k_crfvit(const float* __restrict__ emit, const int* __restrict__ msk,
                         const int* __restrict__ lab, const float* __restrict__ trans,
                         float* __restrict__ nll, int* __restrict__ ptr,
                         float* __restrict__ out){
  int tid = threadIdx.x;
  __shared__ float tr[361];
  __shared__ float al[19];
  __shared__ int tg[256];
  for (int i = tid; i < 361; i += 64) tr[i] = trans[i];

  if (blockIdx.x < 32){
    // ---- CRF forward (NLL) ----
    int b = blockIdx.x;
    const float* eb = emit + (size_t)b*SS*TT;
    const int* mb = msk + b*SS;
    const int* lb = lab + b*SS;
    __syncthreads();
    float gp = 0.f; int ln = 0;
    for (int t = tid; t < SS; t += 64){
      int m = mb[t];
      ln += m;
      if (m){
        int l = lb[t];
        int p = t ? lb[t-1] : START_TAG;
        gp += tr[p*19 + l] + eb[t*19 + l];
      }
    }
    for (int off = 32; off; off >>= 1){ gp += __shfl_down(gp, off); ln += __shfl_down(ln, off); }
    float gold = 0.f;
    if (tid == 0){
      int lt = lb[ln - 1];
      gold = gp + tr[lt*19 + STOP_TAG];
    }
    if (tid < 19) al[tid] = eb[tid] + tr[START_TAG*19 + tid];
    __syncthreads();
    for (int t = 1; t < SS; ++t){
      int m = mb[t];
      float nv = 0.f;
      if (tid < 19){
        float mx = -1e30f;
        for (int p = 0; p < 19; ++p){ float v = al[p] + tr[p*19 + tid]; mx = fmaxf(mx, v); }
        float sum = 0.f;
        for (int p = 0; p < 19; ++p) sum += expf(al[p] + tr[p*19 + tid] - mx);
        nv = mx + logf(sum) + eb[t*19 + tid];
      }
      __syncthreads();
      if (tid < 19 && m) al[tid] = nv;
      __syncthreads();
    }
    if (tid == 0){
      float mx = -1e30f;
      for (int c2 = 0; c2 < 19; ++c2) mx = fmaxf(mx, al[c2] + tr[c2*19 + STOP_TAG]);
      float sum = 0.f;
      for (int c2 = 0; c2 < 19; ++c2) sum += expf(al[c2] + tr[c2*19 + STOP_TAG] - mx);
      nll[b] = (mx + logf(sum)) - gold;
    }
  } else {
    // ---- Viterbi decode ----
    int b = blockIdx.x - 32;
    const float* eb = emit + (size_t)b*SS*TT;
    const int* mb = msk + b*SS;
    int* pb = ptr + (size_t)b*SS*TT;
    if (tid < 19) al[tid] = eb[tid] + tr[START_TAG*19 + tid];   // al doubles as delta
    __syncthreads();
    for (int t = 1; t < SS; ++t){
      int m = mb[t];
      float best = -1e30f; int bp = 0;
      if (tid < 19){
        for (int p = 0; p < 19; ++p){
          float v = al[p] + tr[p*19 + tid];
          if (v > best){ best = v; bp = p; }       // strict > == first-max (jnp.argmax)
        }
      }
      __syncthreads();
      if (tid < 19){
        if (m){ al[tid] = best + eb[t*19 + tid]; pb[t*19 + tid] = bp; }
        else  { pb[t*19 + tid] = tid; }            // identity pass-through when padded
      }
      __syncthreads();
    }
    if (tid == 0){
      float bv = -1e30f; int bl = 0;
      for (int c2 = 0; c2 < 19; ++c2){
        float v = al[c2] + tr[c2*19 + STOP_TAG];
        if (v > bv){ bv = v; bl = c2; }
      }
      tg[SS-1] = bl;
      for (int t = SS-1; t > 0; --t) tg[t-1] = pb[t*19 + tg[t]];
    }
    __syncthreads();
    for (int t = tid; t < SS; t += 64)
      out[1 + b*SS + t] = (float)(tg[t] * mb[t]);
  }
}

// -------- final loss reduce: d_out[0] = sum(nll)/B --------
__global__ void k_final(const float* __restrict__ nll, float* __restrict__ out){
  int tid = threadIdx.x;
  float v = (tid < 32) ? nll[tid] : 0.f;
  for (int off = 32; off; off >>= 1) v += __shfl_down(v, off);
  if (tid == 0) out[0] = v * (1.0f/32.0f);
}

extern "C" void kernel_launch(void* const* d_in, const int* in_sizes, int n_in,
                              void* d_out, int out_size, void* d_ws, size_t ws_size,
                              hipStream_t stream){
  const int*   wi    = (const int*)d_in[0];
  const int*   msk   = (const int*)d_in[1];
  const int*   lab   = (const int*)d_in[2];
  // d_in[3] labels_token, d_in[4] data_type: unused (data_type==1 branch)
  const float* emb   = (const float*)d_in[5];
  const float* Wih_f = (const float*)d_in[6];
  const float* Whh_f = (const float*)d_in[7];
  const float* bih_f = (const float*)d_in[8];
  const float* bhh_f = (const float*)d_in[9];
  const float* Wih_b = (const float*)d_in[10];
  const float* Whh_b = (const float*)d_in[11];
  const float* bih_b = (const float*)d_in[12];
  const float* bhh_b = (const float*)d_in[13];
  const float* Wtag  = (const float*)d_in[14];
  const float* btag  = (const float*)d_in[15];
  const float* trans = (const float*)d_in[16];

  float* ws   = (float*)d_ws;
  float* x    = ws;
  float* WT   = ws + 2490368;
  float* bias = ws + 3112960;
  unsigned int* W16u = (unsigned int*)(ws + 3115008);
  uint4* W16  = (uint4*)W16u;
  float* gin  = ws + 3639296;
  float* hseq = ws + 20416512;
  float* emit = ws + 24610816;
  int*   ptr  = (int*)(ws + 24766464);
  float* nll  = ws + 24922112;
  float* out  = (float*)d_out;

  // allow >64KB dynamic LDS for k_lstm (one-time; host-side attribute set)
  static bool s_attr = false;
  if (!s_attr){
    (void)hipFuncSetAttribute((const void*)k_lstm,
                              hipFuncAttributeMaxDynamicSharedMemorySize,
                              K_LSTM_LDS_BYTES);
    s_attr = true;
  }

  hipLaunchKernelGGL(k_embed,      dim3(2432),    dim3(256),  0, stream, wi, msk, emb, x);
  hipLaunchKernelGGL(k_prep_wt,    dim3(2440),    dim3(256),  0, stream,
                     Wih_f, Wih_b, bih_f, bhh_f, bih_b, bhh_b, WT, bias);
  hipLaunchKernelGGL(k_prep_whh16, dim3(1024),    dim3(256),  0, stream, Whh_f, Whh_b, W16u);
  hipLaunchKernelGGL(k_gemm,       dim3(32,128),  dim3(256),  0, stream, x, WT, bias, gin);
  hipLaunchKernelGGL(k_lstm,       dim3(64),      dim3(512),  K_LSTM_LDS_BYTES, stream,
                     gin, W16, hseq);
  hipLaunchKernelGGL(k_emit,       dim3(608),     dim3(256),  0, stream, hseq, Wtag, btag, emit);
  hipLaunchKernelGGL(k_crfvit,     dim3(64),      dim3(64),   0, stream, emit, msk, lab, trans,
                     nll, ptr, out);
  hipLaunchKernelGGL(k_final,      dim3(1),       dim3(64),   0, stream, nll, out);
}

// Round 3
// 1057.605 us; speedup vs baseline: 2.0172x; 1.0449x over previous
//
#include <hip/hip_runtime.h>
#include <hip/hip_fp16.h>
#include <math.h>

// Problem constants (fixed shapes from the reference)
#define BB 32
#define SS 256
#define EE 300
#define KP 320          // E padded to multiple of 32 (MFMA K)
#define HH 256
#define TT 19           // NUM_TAGS + START + STOP
#define START_TAG 17
#define STOP_TAG 18
#define BS 8192         // B*S
#define GIN_PER_DIR (8192*1024)

// k_lstm weight residency split (per thread, of 16 u-chunks x 4 gates):
//   RCH u-chunks in registers (volatile-asm pinned), 16-RCH u-chunks in LDS.
#define RCH 12                       // 48 uint4 = 192 dwords persistent (VGPR+AGPR)
#define LDS_WCHUNK (16 - RCH)        // 4 chunks -> 16 slots x 512 uint4 = 128 KB
#define K_LSTM_LDS_BYTES ((8192 + 32 + 256) * 16)   // wlds + hsq + glh = 135680 B

typedef _Float16 half8 __attribute__((ext_vector_type(8)));
typedef float    f32x4 __attribute__((ext_vector_type(4)));

__device__ __forceinline__ float sigm(float x){ return 1.0f/(1.0f+expf(-x)); }

#ifdef __has_builtin
#if __has_builtin(__builtin_amdgcn_fdot2)
#define HAVE_FDOT2 1
#endif
#endif

// v_dot2_f32_f16: acc += lo(w)*lo(h) + hi(w)*hi(h), f32 accumulate
__device__ __forceinline__ float dot2(unsigned int w, unsigned int h, float acc){
#ifdef HAVE_FDOT2
  typedef _Float16 h2_t __attribute__((ext_vector_type(2)));
  return __builtin_amdgcn_fdot2(__builtin_bit_cast(h2_t, w),
                                __builtin_bit_cast(h2_t, h), acc, false);
#else
  float r;
  asm("v_dot2_f32_f16 %0, %1, %2, %3" : "=v"(r) : "v"(w), "v"(h), "v"(acc));
  return r;
#endif
}

// volatile-asm 16B load: cannot be duplicated/rematerialized by the compiler,
// so the result MUST stay register-resident across the step loop.
__device__ __forceinline__ uint4 vload_u4(const uint4* p){
  uint4 r;
  asm volatile("global_load_dwordx4 %0, %1, off"
               : "=&v"(r) : "v"(p) : "memory");
  return r;
}

// RNE pack of two f32 values into a half2 dword
__device__ __forceinline__ unsigned int pack_h2(float a, float b){
  unsigned int lo = __half_as_ushort(__float2half(a));
  unsigned int hi = __half_as_ushort(__float2half(b));
  return (hi << 16) | lo;
}

// 16 dot2 = 32 MACs: one k-chunk of 8 (uint4 hu = 8 packed fp16 h) x 4 gates
__device__ __forceinline__ void mac4(uint4 w0, uint4 w1, uint4 w2, uint4 w3, uint4 hu,
                                     float& ai, float& af, float& ag, float& ao){
  ai = dot2(w0.x, hu.x, ai); ai = dot2(w0.y, hu.y, ai); ai = dot2(w0.z, hu.z, ai); ai = dot2(w0.w, hu.w, ai);
  af = dot2(w1.x, hu.x, af); af = dot2(w1.y, hu.y, af); af = dot2(w1.z, hu.z, af); af = dot2(w1.w, hu.w, af);
  ag = dot2(w2.x, hu.x, ag); ag = dot2(w2.y, hu.y, ag); ag = dot2(w2.z, hu.z, ag); ag = dot2(w2.w, hu.w, ag);
  ao = dot2(w3.x, hu.x, ao); ao = dot2(w3.y, hu.y, ao); ao = dot2(w3.z, hu.z, ao); ao = dot2(w3.w, hu.w, ao);
}

// ---------------- ws layout (float offsets) ----------------
// x16   : [BS][320] fp16       off 0          size 1310720 (floats used)
// W16n  : [2048][320] fp16     off 2490368    size 327680  (permuted rows n=(j*4+g)+1024*dir)
// bias2 : [2048]               off 3112960    size 2048
// W16   : fp16 Whh packed      off 3115008    size 262144 floats used (1 MB)
//         uint4 index: (d*64 + q)*512 + tid ; q = u*4+g (u=0..15 k-chunk, g=gate)
//         tid = kpart*256+urow (kpart 2-way) ; dword j holds k = kpart*128 + u*8 + j*2 (+1 hi)
// gin   : [2][BS][1024]        off 3639296    size 16777216 (preacts, interleaved row j*4+g)
// hseq  : [BS][512]            off 20416512   size 4194304
// emit  : [BS][19]             off 24610816   size 155648
// ptr   : [BS][19] (int)       off 24766464   size 155648
// nll   : [32]                 off 24922112

// -------- embed gather + mask -> fp16, pad E to 320 with zeros --------
__global__ void k_embed16(const int* __restrict__ wi, const int* __restrict__ msk,
                          const float* __restrict__ emb, unsigned int* __restrict__ x16){
  int id = blockIdx.x*256 + threadIdx.x;        // BS*40 uint4 slots (320 halves/row)
  if (id >= BS*40) return;
  int row = id / 40, q = id - row*40;
  int base = wi[row]*300;
  float m = (float)msk[row];
  float v[8];
  #pragma unroll
  for (int e = 0; e < 8; ++e){
    int k = q*8 + e;
    v[e] = (k < 300) ? emb[base + k]*m : 0.f;
  }
  uint4 o;
  o.x = pack_h2(v[0], v[1]); o.y = pack_h2(v[2], v[3]);
  o.z = pack_h2(v[4], v[5]); o.w = pack_h2(v[6], v[7]);
  ((uint4*)x16)[id] = o;
}

// -------- Wih -> fp16 panel [2048][320], rows permuted to n=(j*4+g)+1024*dir; + bias --------
__global__ void k_prep_w16n(const float* __restrict__ Wih_f, const float* __restrict__ Wih_b,
                            const float* __restrict__ bih_f, const float* __restrict__ bhh_f,
                            const float* __restrict__ bih_b, const float* __restrict__ bhh_b,
                            unsigned int* __restrict__ w16n, float* __restrict__ bias){
  int id = blockIdx.x*256 + threadIdx.x;
  if (id < 2048*40){
    int n = id / 40, q = id - n*40;
    int dd = n >> 10, r = n & 1023, j = r >> 2, g = r & 3;
    const float* W = dd ? Wih_b : Wih_f;
    int base = (g*256 + j)*300;
    float v[8];
    #pragma unroll
    for (int e = 0; e < 8; ++e){
      int k = q*8 + e;
      v[e] = (k < 300) ? W[base + k] : 0.f;
    }
    uint4 o;
    o.x = pack_h2(v[0], v[1]); o.y = pack_h2(v[2], v[3]);
    o.z = pack_h2(v[4], v[5]); o.w = pack_h2(v[6], v[7]);
    ((uint4*)w16n)[id] = o;
  } else {
    int n = id - 2048*40;
    if (n < 2048){
      int dd = n >> 10, r = n & 1023, j = r >> 2, g = r & 3;
      int orow = g*256 + j;
      bias[n] = dd ? (bih_b[orow] + bhh_b[orow]) : (bih_f[orow] + bhh_f[orow]);
    }
  }
}

// -------- pack Whh to fp16 for k_lstm (layout in ws map) --------
__global__ void k_prep_whh16(const float* __restrict__ Whh_f, const float* __restrict__ Whh_b,
                             unsigned int* __restrict__ out){
  int id = blockIdx.x*256 + threadIdx.x;        // 262144 uints
  int j   = id & 3;
  int u4  = id >> 2;                             // uint4 index
  int tid = u4 & 511;
  int q   = (u4 >> 9) & 63;
  int d   = u4 >> 15;
  int kpart = tid >> 8, urow = tid & 255;
  int u = q >> 2, g = q & 3;
  int k = kpart*128 + u*8 + j*2;
  const float* W = d ? Whh_b : Whh_f;
  float w0 = W[(size_t)(g*256 + urow)*256 + k];
  float w1 = W[(size_t)(g*256 + urow)*256 + k + 1];
  out[id] = pack_h2(w0, w1);
}

// -------- input-gate GEMM via MFMA f16: gin[dd][m][r] = x16[m] . W16n[n] + bias[n] --------
// 64x64 block tile, 4 waves; wave w owns n-strip [bx*64+w*16, +16), M-rep 4.
// No LDS: B panel (1.3 MB) is L2-resident across 128 M-blocks; A streams once.
// Fragment mapping (verified m89/m91): A lane m=l&15 k-group=l>>4 (8 contiguous k),
// B lane n=l&15 same k-group; C col=l&15, row=(l>>4)*4+reg.
__global__ __launch_bounds__(256) void k_gemm(const unsigned short* __restrict__ x16,
      const unsigned short* __restrict__ w16n, const float* __restrict__ bias,
      float* __restrict__ gin){
  int tid = threadIdx.x;
  int l = tid & 63, w = tid >> 6;
  int lm = l & 15, kg = l >> 4;
  int m0 = blockIdx.y * 64;
  int nw = blockIdx.x * 64 + w*16;
  const uint4* A  = ((const uint4*)x16) + (size_t)(m0 + lm)*40 + kg;   // row = 40 uint4
  const uint4* Bp = ((const uint4*)w16n) + (size_t)(nw + lm)*40 + kg;
  f32x4 acc0 = {0.f,0.f,0.f,0.f}, acc1 = acc0, acc2 = acc0, acc3 = acc0;
  #pragma unroll
  for (int kt = 0; kt < 10; ++kt){
    half8 b  = __builtin_bit_cast(half8, Bp[kt*4]);
    half8 a0 = __builtin_bit_cast(half8, A[       kt*4]);
    half8 a1 = __builtin_bit_cast(half8, A[ 640 + kt*4]);
    half8 a2 = __builtin_bit_cast(half8, A[1280 + kt*4]);
    half8 a3 = __builtin_bit_cast(half8, A[1920 + kt*4]);
    acc0 = __builtin_amdgcn_mfma_f32_16x16x32_f16(a0, b, acc0, 0, 0, 0);
    acc1 = __builtin_amdgcn_mfma_f32_16x16x32_f16(a1, b, acc1, 0, 0, 0);
    acc2 = __builtin_amdgcn_mfma_f32_16x16x32_f16(a2, b, acc2, 0, 0, 0);
    acc3 = __builtin_amdgcn_mfma_f32_16x16x32_f16(a3, b, acc3, 0, 0, 0);
  }
  int n = nw + lm;
  float bn = bias[n];
  int dd = n >> 10, r = n & 1023;
  float* go = gin + (size_t)dd*GIN_PER_DIR + r;
  int mb = m0 + kg*4;
  #pragma unroll
  for (int reg = 0; reg < 4; ++reg){
    go[(size_t)(mb +  0 + reg)*1024] = acc0[reg] + bn;
    go[(size_t)(mb + 16 + reg)*1024] = acc1[reg] + bn;
    go[(size_t)(mb + 32 + reg)*1024] = acc2[reg] + bn;
    go[(size_t)(mb + 48 + reg)*1024] = acc3[reg] + bn;
  }
}

// -------- BiLSTM recurrence: fully-resident weights (VGPR/AGPR + LDS), zero L2 stream --------
__global__ __launch_bounds__(512, 2) void k_lstm(const float* __restrict__ gin,
                 const uint4* __restrict__ W16, float* __restrict__ hseq){
  extern __shared__ uint4 smem[];
  uint4*  wlds = smem;                       // [16 slots][512] = 8192 uint4 (128 KB)
  uint4*  hsq  = smem + 8192;                // 32 uint4: h packed fp16 (512 B)
  float4* glh  = (float4*)(smem + 8224);     // 256 float4: kpart=1 partials (4 KB)

  int tid = threadIdx.x;
  int b = blockIdx.x & 31, d = blockIdx.x >> 5;
  int kpart = tid >> 8;                              // 0..1
  const uint4* wq = W16 + (size_t)d*64*512 + tid;    // + q*512 per q
  const float* gb = gin + (size_t)d*GIN_PER_DIR + (size_t)b*SS*1024;

  // ---- stage LDS weight chunks (u = RCH..15 -> q = 48..63), once ----
  #pragma unroll
  for (int q = 4*RCH; q < 64; ++q)
    wlds[(q - 4*RCH)*512 + tid] = wq[(size_t)q*512];

  if (tid < 32) hsq[tid] = make_uint4(0u,0u,0u,0u);

  // ---- pin register weight chunks (q = 0..47) via volatile asm ----
  uint4 wr[4*RCH];
  #pragma unroll
  for (int q = 0; q < 4*RCH; ++q) wr[q] = vload_u4(wq + (size_t)q*512);
  asm volatile("s_waitcnt vmcnt(0)" ::: "memory");
  __builtin_amdgcn_sched_barrier(0);

  float c = 0.f;
  __syncthreads();

  const uint4* wl = wlds + tid;
  for (int s = 0; s < SS; ++s){
    int t = d ? (SS-1-s) : s;
    float4 gv = make_float4(0.f,0.f,0.f,0.f);
    if (tid < 256) gv = ((const float4*)(gb + (size_t)t*1024))[tid];  // prefetch preacts

    float ai = 0.f, af = 0.f, ag = 0.f, ao = 0.f;
    // register-resident chunks
    #pragma unroll
    for (int u = 0; u < RCH; ++u){
      uint4 hu = hsq[kpart*16 + u];                  // wave-uniform LDS broadcast
      mac4(wr[u*4+0], wr[u*4+1], wr[u*4+2], wr[u*4+3], hu, ai, af, ag, ao);
    }
    // LDS-resident chunks
    #pragma unroll
    for (int uu = 0; uu < LDS_WCHUNK; ++uu){
      uint4 hu = hsq[kpart*16 + RCH + uu];
      uint4 w0 = wl[(uu*4+0)*512];
      uint4 w1 = wl[(uu*4+1)*512];
      uint4 w2 = wl[(uu*4+2)*512];
      uint4 w3 = wl[(uu*4+3)*512];
      mac4(w0, w1, w2, w3, hu, ai, af, ag, ao);
    }
    if (kpart) glh[tid & 255] = make_float4(ai, af, ag, ao);
    __syncthreads();
    if (tid < 256){
      float4 p1 = glh[tid];
      float iv = sigm (ai + p1.x + gv.x);
      float fv = sigm (af + p1.y + gv.y);
      float gg = tanhf(ag + p1.z + gv.z);
      float ov = sigm (ao + p1.w + gv.w);
      c = fv*c + iv*gg;
      float hv = ov*tanhf(c);
      hseq[((size_t)(b*SS + t))*512 + d*256 + tid] = hv;
      float hp = __shfl_xor(hv, 1);                  // partner h within wave
      if (!(tid & 1))
        ((unsigned int*)hsq)[tid >> 1] = pack_h2(hv, hp);
    }
    __syncthreads();
  }
}

// -------- tag logits: emit[row][t] = hseq[row] . W_tag[t] + b_tag[t] --------
__global__ void k_emit(const float* __restrict__ hseq, const float* __restrict__ Wtag,
                       const float* __restrict__ btag, float* __restrict__ emit){
  int id = blockIdx.x*256 + threadIdx.x;
  if (id >= BS*TT) return;
  int row = id / TT, tg = id - row*TT;
  const float4* hp = (const float4*)(hseq + (size_t)row*512);
  const float4* wp = (const float4*)(Wtag + (size_t)tg*512);
  float acc = btag[tg];
  #pragma unroll 8
  for (int k = 0; k < 128; ++k){
    float4 h = hp[k], w = wp[k];
    acc += h.x*w.x + h.y*w.y + h.z*w.z + h.w*w.w;
  }
  emit[id] = acc;
}

// -------- fused CRF NLL + Viterbi: blocks 0..31 CRF(b), 32..63 Viterbi(b-32) --------
__global__ void k_crfvit(const float* __restrict__ emit, const int* __restrict__ msk,
                         const int* __restrict__ lab, const float* __restrict__ trans,
                         float* __restrict__ nll, int* __restrict__ ptr,
                         float* __restrict__ out){
  int tid = threadIdx.x;
  __shared__ float tr[361];
  __shared__ float al[19];
  __shared__ int tg[256];
  for (int i = tid; i < 361; i += 64) tr[i] = trans[i];

  if (blockIdx.x < 32){
    // ---- CRF forward (NLL) ----
    int b = blockIdx.x;
    const float* eb = emit + (size_t)b*SS*TT;
    const int* mb = msk + b*SS;
    const int* lb = lab + b*SS;
    __syncthreads();
    float gp = 0.f; int ln = 0;
    for (int t = tid; t < SS; t += 64){
      int m = mb[t];
      ln += m;
      if (m){
        int l = lb[t];
        int p = t ? lb[t-1] : START_TAG;
        gp += tr[p*19 + l] + eb[t*19 + l];
      }
    }
    for (int off = 32; off; off >>= 1){ gp += __shfl_down(gp, off); ln += __shfl_down(ln, off); }
    float gold = 0.f;
    if (tid == 0){
      int lt = lb[ln - 1];
      gold = gp + tr[lt*19 + STOP_TAG];
    }
    if (tid < 19) al[tid] = eb[tid] + tr[START_TAG*19 + tid];
    __syncthreads();
    for (int t = 1; t < SS; ++t){
      int m = mb[t];
      float nv = 0.f;
      if (tid < 19){
        float mx = -1e30f;
        for (int p = 0; p < 19; ++p){ float v = al[p] + tr[p*19 + tid]; mx = fmaxf(mx, v); }
        float sum = 0.f;
        for (int p = 0; p < 19; ++p) sum += expf(al[p] + tr[p*19 + tid] - mx);
        nv = mx + logf(sum) + eb[t*19 + tid];
      }
      __syncthreads();
      if (tid < 19 && m) al[tid] = nv;
      __syncthreads();
    }
    if (tid == 0){
      float mx = -1e30f;
      for (int c2 = 0; c2 < 19; ++c2) mx = fmaxf(mx, al[c2] + tr[c2*19 + STOP_TAG]);
      float sum = 0.f;
      for (int c2 = 0; c2 < 19; ++c2) sum += expf(al[c2] + tr[c2*19 + STOP_TAG] - mx);
      nll[b] = (mx + logf(sum)) - gold;
    }
  } else {
    // ---- Viterbi decode ----
    int b = blockIdx.x - 32;
    const float* eb = emit + (size_t)b*SS*TT;
    const int* mb = msk + b*SS;
    int* pb = ptr + (size_t)b*SS*TT;
    if (tid < 19) al[tid] = eb[tid] + tr[START_TAG*19 + tid];   // al doubles as delta
    __syncthreads();
    for (int t = 1; t < SS; ++t){
      int m = mb[t];
      float best = -1e30f; int bp = 0;
      if (tid < 19){
        for (int p = 0; p < 19; ++p){
          float v = al[p] + tr[p*19 + tid];
          if (v > best){ best = v; bp = p; }       // strict > == first-max (jnp.argmax)
        }
      }
      __syncthreads();
      if (tid < 19){
        if (m){ al[tid] = best + eb[t*19 + tid]; pb[t*19 + tid] = bp; }
        else  { pb[t*19 + tid] = tid; }            // identity pass-through when padded
      }
      __syncthreads();
    }
    if (tid == 0){
      float bv = -1e30f; int bl = 0;
      for (int c2 = 0; c2 < 19; ++c2){
        float v = al[c2] + tr[c2*19 + STOP_TAG];
        if (v > bv){ bv = v; bl = c2; }
      }
      tg[SS-1] = bl;
      for (int t = SS-1; t > 0; --t) tg[t-1] = pb[t*19 + tg[t]];
    }
    __syncthreads();
    for (int t = tid; t < SS; t += 64)
      out[1 + b*SS + t] = (float)(tg[t] * mb[t]);
  }
}

// -------- final loss reduce: d_out[0] = sum(nll)/B --------
__global__ void k_final(const float* __restrict__ nll, float* __restrict__ out){
  int tid = threadIdx.x;
  float v = (tid < 32) ? nll[tid] : 0.f;
  for (int off = 32; off; off >>= 1) v += __shfl_down(v, off);
  if (tid == 0) out[0] = v * (1.0f/32.0f);
}

extern "C" void kernel_launch(void* const* d_in, const int* in_sizes, int n_in,
                              void* d_out, int out_size, void* d_ws, size_t ws_size,
                              hipStream_t stream){
  const int*   wi    = (const int*)d_in[0];
  const int*   msk   = (const int*)d_in[1];
  const int*   lab   = (const int*)d_in[2];
  // d_in[3] labels_token, d_in[4] data_type: unused (data_type==1 branch)
  const float* emb   = (const float*)d_in[5];
  const float* Wih_f = (const float*)d_in[6];
  const float* Whh_f = (const float*)d_in[7];
  const float* bih_f = (const float*)d_in[8];
  const float* bhh_f = (const float*)d_in[9];
  const float* Wih_b = (const float*)d_in[10];
  const float* Whh_b = (const float*)d_in[11];
  const float* bih_b = (const float*)d_in[12];
  const float* bhh_b = (const float*)d_in[13];
  const float* Wtag  = (const float*)d_in[14];
  const float* btag  = (const float*)d_in[15];
  const float* trans = (const float*)d_in[16];

  float* ws   = (float*)d_ws;
  unsigned short* x16  = (unsigned short*)ws;
  unsigned short* w16n = (unsigned short*)(ws + 2490368);
  float* bias = ws + 3112960;
  unsigned int* W16u = (unsigned int*)(ws + 3115008);
  uint4* W16  = (uint4*)W16u;
  float* gin  = ws + 3639296;
  float* hseq = ws + 20416512;
  float* emit = ws + 24610816;
  int*   ptr  = (int*)(ws + 24766464);
  float* nll  = ws + 24922112;
  float* out  = (float*)d_out;

  // allow >64KB dynamic LDS for k_lstm (one-time; host-side attribute set)
  static bool s_attr = false;
  if (!s_attr){
    (void)hipFuncSetAttribute((const void*)k_lstm,
                              hipFuncAttributeMaxDynamicSharedMemorySize,
                              K_LSTM_LDS_BYTES);
    s_attr = true;
  }

  hipLaunchKernelGGL(k_embed16,    dim3(1280),    dim3(256),  0, stream, wi, msk, emb,
                     (unsigned int*)x16);
  hipLaunchKernelGGL(k_prep_w16n,  dim3(329),     dim3(256),  0, stream,
                     Wih_f, Wih_b, bih_f, bhh_f, bih_b, bhh_b, (unsigned int*)w16n, bias);
  hipLaunchKernelGGL(k_prep_whh16, dim3(1024),    dim3(256),  0, stream, Whh_f, Whh_b, W16u);
  hipLaunchKernelGGL(k_gemm,       dim3(32,128),  dim3(256),  0, stream, x16, w16n, bias, gin);
  hipLaunchKernelGGL(k_lstm,       dim3(64),      dim3(512),  K_LSTM_LDS_BYTES, stream,
                     gin, W16, hseq);
  hipLaunchKernelGGL(k_emit,       dim3(608),     dim3(256),  0, stream, hseq, Wtag, btag, emit);
  hipLaunchKernelGGL(k_crfvit,     dim3(64),      dim3(64),   0, stream, emit, msk, lab, trans,
                     nll, ptr, out);
  hipLaunchKernelGGL(k_final,      dim3(1),       dim3(64),   0, stream, nll, out);
}

// Round 4
// 860.584 us; speedup vs baseline: 2.4790x; 1.2289x over previous
//
#include <hip/hip_runtime.h>
#include <hip/hip_fp16.h>
#include <math.h>

// Problem constants (fixed shapes from the reference)
#define BB 32
#define SS 256
#define EE 300
#define KP 320          // E padded to multiple of 32 (MFMA K)
#define HH 256
#define TT 19           // NUM_TAGS + START + STOP
#define START_TAG 17
#define STOP_TAG 18
#define BS 8192         // B*S
#define GIN_PER_DIR (8192*1024)

// k_lstm weight residency split (per thread, of 16 u-chunks x 4 gates):
//   RCH u-chunks in registers (volatile-asm pinned), 16-RCH u-chunks in LDS.
#define RCH 12                       // 48 uint4 = 192 dwords persistent (VGPR+AGPR)
#define LDS_WCHUNK (16 - RCH)        // 4 chunks -> 16 slots x 512 uint4 = 128 KB
#define K_LSTM_LDS_BYTES ((8192 + 32 + 256) * 16)   // wlds + hsq + glh = 135680 B

// merged prep kernel block ranges
#define EMBED_BLKS 1280
#define W16N_BLKS  329
#define WHH_BLKS   1024

typedef _Float16 half8 __attribute__((ext_vector_type(8)));
typedef float    f32x4 __attribute__((ext_vector_type(4)));

// ---- fast transcendentals (v_exp_f32 / v_rcp_f32 based) ----
__device__ __forceinline__ float fexp(float x){
#if defined(__has_builtin) && __has_builtin(__builtin_amdgcn_exp2f)
  return __builtin_amdgcn_exp2f(x * 1.4426950408889634f);
#else
  return expf(x);
#endif
}
__device__ __forceinline__ float frcp(float x){
#if defined(__has_builtin) && __has_builtin(__builtin_amdgcn_rcpf)
  return __builtin_amdgcn_rcpf(x);
#else
  return 1.0f/x;
#endif
}
__device__ __forceinline__ float sigm(float x){ return frcp(1.0f + fexp(-x)); }
__device__ __forceinline__ float ftanh(float x){
  x = fminf(fmaxf(x, -20.f), 20.f);               // keep e finite; tanh saturated anyway
  float e = fexp(2.0f*x);
  return (e - 1.0f) * frcp(e + 1.0f);
}

#ifdef __has_builtin
#if __has_builtin(__builtin_amdgcn_fdot2)
#define HAVE_FDOT2 1
#endif
#endif

// v_dot2_f32_f16: acc += lo(w)*lo(h) + hi(w)*hi(h), f32 accumulate
__device__ __forceinline__ float dot2(unsigned int w, unsigned int h, float acc){
#ifdef HAVE_FDOT2
  typedef _Float16 h2_t __attribute__((ext_vector_type(2)));
  return __builtin_amdgcn_fdot2(__builtin_bit_cast(h2_t, w),
                                __builtin_bit_cast(h2_t, h), acc, false);
#else
  float r;
  asm("v_dot2_f32_f16 %0, %1, %2, %3" : "=v"(r) : "v"(w), "v"(h), "v"(acc));
  return r;
#endif
}

// volatile-asm 16B load: cannot be duplicated/rematerialized by the compiler,
// so the result MUST stay register-resident across the step loop.
__device__ __forceinline__ uint4 vload_u4(const uint4* p){
  uint4 r;
  asm volatile("global_load_dwordx4 %0, %1, off"
               : "=&v"(r) : "v"(p) : "memory");
  return r;
}

// RNE pack of two f32 values into a half2 dword
__device__ __forceinline__ unsigned int pack_h2(float a, float b){
  unsigned int lo = __half_as_ushort(__float2half(a));
  unsigned int hi = __half_as_ushort(__float2half(b));
  return (hi << 16) | lo;
}

// 16 dot2 = 32 MACs: one k-chunk of 8 (uint4 hu = 8 packed fp16 h) x 4 gates
__device__ __forceinline__ void mac4(uint4 w0, uint4 w1, uint4 w2, uint4 w3, uint4 hu,
                                     float& ai, float& af, float& ag, float& ao){
  ai = dot2(w0.x, hu.x, ai); ai = dot2(w0.y, hu.y, ai); ai = dot2(w0.z, hu.z, ai); ai = dot2(w0.w, hu.w, ai);
  af = dot2(w1.x, hu.x, af); af = dot2(w1.y, hu.y, af); af = dot2(w1.z, hu.z, af); af = dot2(w1.w, hu.w, af);
  ag = dot2(w2.x, hu.x, ag); ag = dot2(w2.y, hu.y, ag); ag = dot2(w2.z, hu.z, ag); ag = dot2(w2.w, hu.w, ag);
  ao = dot2(w3.x, hu.x, ao); ao = dot2(w3.y, hu.y, ao); ao = dot2(w3.z, hu.z, ao); ao = dot2(w3.w, hu.w, ao);
}

// ---------------- ws layout (float offsets) ----------------
// x16   : [BS][320] fp16       off 0          size 1310720 (floats used)
// W16n  : [2048][320] fp16     off 2490368    size 327680  (permuted rows n=(j*4+g)+1024*dir)
// bias2 : [2048]               off 3112960    size 2048
// W16   : fp16 Whh packed      off 3115008    size 262144 floats used (1 MB)
// gin   : [2][BS][1024]        off 3639296    size 16777216 (preacts, interleaved row j*4+g)
// hseq  : [BS][512]            off 20416512   size 4194304
// emit  : [BS][19]             off 24610816   size 155648
// nll   : [32]                 off 24922112

// -------- merged prep: embed-gather+fp16 | Wih fp16 panel + bias | Whh fp16 pack --------
__global__ void k_prep(const int* __restrict__ wi, const int* __restrict__ msk,
                       const float* __restrict__ emb,
                       const float* __restrict__ Wih_f, const float* __restrict__ Wih_b,
                       const float* __restrict__ bih_f, const float* __restrict__ bhh_f,
                       const float* __restrict__ bih_b, const float* __restrict__ bhh_b,
                       const float* __restrict__ Whh_f, const float* __restrict__ Whh_b,
                       unsigned int* __restrict__ x16, unsigned int* __restrict__ w16n,
                       float* __restrict__ bias, unsigned int* __restrict__ whh16){
  unsigned bx = blockIdx.x;
  if (bx < EMBED_BLKS){
    // ---- embed gather + mask -> fp16, pad E to 320 with zeros ----
    int id = bx*256 + threadIdx.x;               // BS*40 uint4 slots (320 halves/row)
    if (id >= BS*40) return;
    int row = id / 40, q = id - row*40;
    int base = wi[row]*300;
    float m = (float)msk[row];
    float v[8];
    #pragma unroll
    for (int e = 0; e < 8; ++e){
      int k = q*8 + e;
      v[e] = (k < 300) ? emb[base + k]*m : 0.f;
    }
    uint4 o;
    o.x = pack_h2(v[0], v[1]); o.y = pack_h2(v[2], v[3]);
    o.z = pack_h2(v[4], v[5]); o.w = pack_h2(v[6], v[7]);
    ((uint4*)x16)[id] = o;
  } else if (bx < EMBED_BLKS + W16N_BLKS){
    // ---- Wih -> fp16 panel [2048][320], rows permuted to n=(j*4+g)+1024*dir; + bias ----
    int id = (bx - EMBED_BLKS)*256 + threadIdx.x;
    if (id < 2048*40){
      int n = id / 40, q = id - n*40;
      int dd = n >> 10, r = n & 1023, j = r >> 2, g = r & 3;
      const float* W = dd ? Wih_b : Wih_f;
      int base = (g*256 + j)*300;
      float v[8];
      #pragma unroll
      for (int e = 0; e < 8; ++e){
        int k = q*8 + e;
        v[e] = (k < 300) ? W[base + k] : 0.f;
      }
      uint4 o;
      o.x = pack_h2(v[0], v[1]); o.y = pack_h2(v[2], v[3]);
      o.z = pack_h2(v[4], v[5]); o.w = pack_h2(v[6], v[7]);
      ((uint4*)w16n)[id] = o;
    } else {
      int n = id - 2048*40;
      if (n < 2048){
        int dd = n >> 10, r = n & 1023, j = r >> 2, g = r & 3;
        int orow = g*256 + j;
        bias[n] = dd ? (bih_b[orow] + bhh_b[orow]) : (bih_f[orow] + bhh_f[orow]);
      }
    }
  } else {
    // ---- pack Whh to fp16 (k_lstm layout) ----
    int id = (bx - EMBED_BLKS - W16N_BLKS)*256 + threadIdx.x;   // 262144 uints
    int j   = id & 3;
    int u4  = id >> 2;                             // uint4 index
    int tid = u4 & 511;
    int q   = (u4 >> 9) & 63;
    int d   = u4 >> 15;
    int kpart = tid >> 8, urow = tid & 255;
    int u = q >> 2, g = q & 3;
    int k = kpart*128 + u*8 + j*2;
    const float* W = d ? Whh_b : Whh_f;
    float w0 = W[(size_t)(g*256 + urow)*256 + k];
    float w1 = W[(size_t)(g*256 + urow)*256 + k + 1];
    whh16[id] = pack_h2(w0, w1);
  }
}

// -------- input-gate GEMM via MFMA f16: gin[dd][m][r] = x16[m] . W16n[n] + bias[n] --------
// 64x64 block tile, 4 waves; wave w owns n-strip [bx*64+w*16, +16), M-rep 4. No LDS.
// Fragment mapping (verified m89/m91): A lane m=l&15 k-group=l>>4 (8 contiguous k),
// B lane n=l&15 same k-group; C col=l&15, row=(l>>4)*4+reg.
__global__ __launch_bounds__(256) void k_gemm(const unsigned short* __restrict__ x16,
      const unsigned short* __restrict__ w16n, const float* __restrict__ bias,
      float* __restrict__ gin){
  int tid = threadIdx.x;
  int l = tid & 63, w = tid >> 6;
  int lm = l & 15, kg = l >> 4;
  int m0 = blockIdx.y * 64;
  int nw = blockIdx.x * 64 + w*16;
  const uint4* A  = ((const uint4*)x16) + (size_t)(m0 + lm)*40 + kg;   // row = 40 uint4
  const uint4* Bp = ((const uint4*)w16n) + (size_t)(nw + lm)*40 + kg;
  f32x4 acc0 = {0.f,0.f,0.f,0.f}, acc1 = acc0, acc2 = acc0, acc3 = acc0;
  #pragma unroll
  for (int kt = 0; kt < 10; ++kt){
    half8 b  = __builtin_bit_cast(half8, Bp[kt*4]);
    half8 a0 = __builtin_bit_cast(half8, A[       kt*4]);
    half8 a1 = __builtin_bit_cast(half8, A[ 640 + kt*4]);
    half8 a2 = __builtin_bit_cast(half8, A[1280 + kt*4]);
    half8 a3 = __builtin_bit_cast(half8, A[1920 + kt*4]);
    acc0 = __builtin_amdgcn_mfma_f32_16x16x32_f16(a0, b, acc0, 0, 0, 0);
    acc1 = __builtin_amdgcn_mfma_f32_16x16x32_f16(a1, b, acc1, 0, 0, 0);
    acc2 = __builtin_amdgcn_mfma_f32_16x16x32_f16(a2, b, acc2, 0, 0, 0);
    acc3 = __builtin_amdgcn_mfma_f32_16x16x32_f16(a3, b, acc3, 0, 0, 0);
  }
  int n = nw + lm;
  float bn = bias[n];
  int dd = n >> 10, r = n & 1023;
  float* go = gin + (size_t)dd*GIN_PER_DIR + r;
  int mb = m0 + kg*4;
  #pragma unroll
  for (int reg = 0; reg < 4; ++reg){
    go[(size_t)(mb +  0 + reg)*1024] = acc0[reg] + bn;
    go[(size_t)(mb + 16 + reg)*1024] = acc1[reg] + bn;
    go[(size_t)(mb + 32 + reg)*1024] = acc2[reg] + bn;
    go[(size_t)(mb + 48 + reg)*1024] = acc3[reg] + bn;
  }
}

// -------- BiLSTM recurrence: fully-resident weights (VGPR/AGPR + LDS), zero L2 stream --------
__global__ __launch_bounds__(512, 2) void k_lstm(const float* __restrict__ gin,
                 const uint4* __restrict__ W16, float* __restrict__ hseq){
  extern __shared__ uint4 smem[];
  uint4*  wlds = smem;                       // [16 slots][512] = 8192 uint4 (128 KB)
  uint4*  hsq  = smem + 8192;                // 32 uint4: h packed fp16 (512 B)
  float4* glh  = (float4*)(smem + 8224);     // 256 float4: kpart=1 partials (4 KB)

  int tid = threadIdx.x;
  int b = blockIdx.x & 31, d = blockIdx.x >> 5;
  int kpart = tid >> 8;                              // 0..1
  const uint4* wq = W16 + (size_t)d*64*512 + tid;    // + q*512 per q
  const float* gb = gin + (size_t)d*GIN_PER_DIR + (size_t)b*SS*1024;

  // ---- stage LDS weight chunks (u = RCH..15 -> q = 48..63), once ----
  #pragma unroll
  for (int q = 4*RCH; q < 64; ++q)
    wlds[(q - 4*RCH)*512 + tid] = wq[(size_t)q*512];

  if (tid < 32) hsq[tid] = make_uint4(0u,0u,0u,0u);

  // ---- pin register weight chunks (q = 0..47) via volatile asm ----
  uint4 wr[4*RCH];
  #pragma unroll
  for (int q = 0; q < 4*RCH; ++q) wr[q] = vload_u4(wq + (size_t)q*512);
  asm volatile("s_waitcnt vmcnt(0)" ::: "memory");
  __builtin_amdgcn_sched_barrier(0);

  float c = 0.f;
  __syncthreads();

  const uint4* wl = wlds + tid;
  for (int s = 0; s < SS; ++s){
    int t = d ? (SS-1-s) : s;
    float4 gv = make_float4(0.f,0.f,0.f,0.f);
    if (tid < 256) gv = ((const float4*)(gb + (size_t)t*1024))[tid];  // prefetch preacts

    float ai = 0.f, af = 0.f, ag = 0.f, ao = 0.f;
    // register-resident chunks
    #pragma unroll
    for (int u = 0; u < RCH; ++u){
      uint4 hu = hsq[kpart*16 + u];                  // wave-uniform LDS broadcast
      mac4(wr[u*4+0], wr[u*4+1], wr[u*4+2], wr[u*4+3], hu, ai, af, ag, ao);
    }
    // LDS-resident chunks
    #pragma unroll
    for (int uu = 0; uu < LDS_WCHUNK; ++uu){
      uint4 hu = hsq[kpart*16 + RCH + uu];
      uint4 w0 = wl[(uu*4+0)*512];
      uint4 w1 = wl[(uu*4+1)*512];
      uint4 w2 = wl[(uu*4+2)*512];
      uint4 w3 = wl[(uu*4+3)*512];
      mac4(w0, w1, w2, w3, hu, ai, af, ag, ao);
    }
    if (kpart) glh[tid & 255] = make_float4(ai, af, ag, ao);
    __syncthreads();
    if (tid < 256){
      float4 p1 = glh[tid];
      float iv = sigm (ai + p1.x + gv.x);
      float fv = sigm (af + p1.y + gv.y);
      float gg = ftanh(ag + p1.z + gv.z);
      float ov = sigm (ao + p1.w + gv.w);
      c = fv*c + iv*gg;
      float hv = ov*ftanh(c);
      hseq[((size_t)(b*SS + t))*512 + d*256 + tid] = hv;
      float hp = __shfl_xor(hv, 1);                  // partner h within wave
      if (!(tid & 1))
        ((unsigned int*)hsq)[tid >> 1] = pack_h2(hv, hp);
    }
    __syncthreads();
  }
}

// -------- tag logits: emit[row][t] = hseq[row] . W_tag[t] + b_tag[t] --------
__global__ void k_emit(const float* __restrict__ hseq, const float* __restrict__ Wtag,
                       const float* __restrict__ btag, float* __restrict__ emit){
  int id = blockIdx.x*256 + threadIdx.x;
  if (id >= BS*TT) return;
  int row = id / TT, tg = id - row*TT;
  const float4* hp = (const float4*)(hseq + (size_t)row*512);
  const float4* wp = (const float4*)(Wtag + (size_t)tg*512);
  float acc = btag[tg];
  #pragma unroll 8
  for (int k = 0; k < 128; ++k){
    float4 h = hp[k], w = wp[k];
    acc += h.x*w.x + h.y*w.y + h.z*w.z + h.w*w.w;
  }
  emit[id] = acc;
}

// -------- fused CRF NLL + Viterbi, v2: all per-batch state LDS-resident --------
// blocks 0..31 CRF(b), 32..63 Viterbi(b-32). emit row (19.5 KB), mask, labels and
// Viterbi back-pointers (ushort) staged in LDS before the serial t-loop, so the
// 255-step recurrences and the backtrack chain never touch global memory.
__global__ __launch_bounds__(64) void k_crfvit(const float* __restrict__ emit,
                         const int* __restrict__ msk,
                         const int* __restrict__ lab, const float* __restrict__ trans,
                         float* __restrict__ nll, float* __restrict__ out){
  int tid = threadIdx.x;
  __shared__ float tr[361];
  __shared__ float eb[SS*TT];          // 19456 B: this batch's emit row
  __shared__ int   ml[SS];             // mask
  __shared__ int   ll[SS];             // labels (CRF only)
  __shared__ unsigned short pv[SS*TT]; // viterbi back-pointers (9728 B)
  __shared__ float al[TT];
  __shared__ int   tg[SS];

  int b = blockIdx.x & 31;
  const float* ebg = emit + (size_t)b*SS*TT;
  for (int i = tid; i < 361; i += 64) tr[i] = trans[i];
  for (int i = tid; i < SS*TT; i += 64) eb[i] = ebg[i];
  for (int i = tid; i < SS; i += 64) ml[i] = msk[b*SS + i];

  if (blockIdx.x < 32){
    // ---- CRF forward (NLL) ----
    for (int i = tid; i < SS; i += 64) ll[i] = lab[b*SS + i];
    __syncthreads();
    float gp = 0.f; int ln = 0;
    for (int t = tid; t < SS; t += 64){
      int m = ml[t];
      ln += m;
      if (m){
        int l = ll[t];
        int p = t ? ll[t-1] : START_TAG;
        gp += tr[p*19 + l] + eb[t*19 + l];
      }
    }
    for (int off = 32; off; off >>= 1){ gp += __shfl_down(gp, off); ln += __shfl_down(ln, off); }
    float gold = 0.f;
    if (tid == 0){
      int lt = ll[ln - 1];
      gold = gp + tr[lt*19 + STOP_TAG];
    }
    if (tid < 19) al[tid] = eb[tid] + tr[START_TAG*19 + tid];
    __syncthreads();
    for (int t = 1; t < SS; ++t){
      float nv = 0.f;
      if (tid < 19){
        float mx = -1e30f;
        #pragma unroll
        for (int p = 0; p < 19; ++p){ float v = al[p] + tr[p*19 + tid]; mx = fmaxf(mx, v); }
        float sum = 0.f;
        #pragma unroll
        for (int p = 0; p < 19; ++p) sum += fexp(al[p] + tr[p*19 + tid] - mx);
        nv = mx + logf(sum) + eb[t*19 + tid];
      }
      __syncthreads();
      if (tid < 19 && ml[t]) al[tid] = nv;
      __syncthreads();
    }
    if (tid == 0){
      float mx = -1e30f;
      for (int c2 = 0; c2 < 19; ++c2) mx = fmaxf(mx, al[c2] + tr[c2*19 + STOP_TAG]);
      float sum = 0.f;
      for (int c2 = 0; c2 < 19; ++c2) sum += fexp(al[c2] + tr[c2*19 + STOP_TAG] - mx);
      nll[b] = (mx + logf(sum)) - gold;
    }
  } else {
    // ---- Viterbi decode (LDS back-pointers + LDS backtrack) ----
    if (tid < 19) al[tid] = eb[tid] + tr[START_TAG*19 + tid];   // al doubles as delta
    __syncthreads();
    for (int t = 1; t < SS; ++t){
      int m = ml[t];
      float best = -1e30f; int bp = 0;
      if (tid < 19){
        #pragma unroll
        for (int p = 0; p < 19; ++p){
          float v = al[p] + tr[p*19 + tid];
          if (v > best){ best = v; bp = p; }       // strict > == first-max (jnp.argmax)
        }
      }
      __syncthreads();
      if (tid < 19){
        if (m){ al[tid] = best + eb[t*19 + tid]; pv[t*19 + tid] = (unsigned short)bp; }
        else  { pv[t*19 + tid] = (unsigned short)tid; }   // identity pass-through
      }
      __syncthreads();
    }
    if (tid == 0){
      float bv = -1e30f; int bl = 0;
      for (int c2 = 0; c2 < 19; ++c2){
        float v = al[c2] + tr[c2*19 + STOP_TAG];
        if (v > bv){ bv = v; bl = c2; }
      }
      tg[SS-1] = bl;
      for (int t = SS-1; t > 0; --t) tg[t-1] = pv[t*19 + tg[t]];
    }
    __syncthreads();
    for (int t = tid; t < SS; t += 64)
      out[1 + b*SS + t] = (float)(tg[t] * ml[t]);
  }
}

// -------- final loss reduce: d_out[0] = sum(nll)/B --------
__global__ void k_final(const float* __restrict__ nll, float* __restrict__ out){
  int tid = threadIdx.x;
  float v = (tid < 32) ? nll[tid] : 0.f;
  for (int off = 32; off; off >>= 1) v += __shfl_down(v, off);
  if (tid == 0) out[0] = v * (1.0f/32.0f);
}

extern "C" void kernel_launch(void* const* d_in, const int* in_sizes, int n_in,
                              void* d_out, int out_size, void* d_ws, size_t ws_size,
                              hipStream_t stream){
  const int*   wi    = (const int*)d_in[0];
  const int*   msk   = (const int*)d_in[1];
  const int*   lab   = (const int*)d_in[2];
  // d_in[3] labels_token, d_in[4] data_type: unused (data_type==1 branch)
  const float* emb   = (const float*)d_in[5];
  const float* Wih_f = (const float*)d_in[6];
  const float* Whh_f = (const float*)d_in[7];
  const float* bih_f = (const float*)d_in[8];
  const float* bhh_f = (const float*)d_in[9];
  const float* Wih_b = (const float*)d_in[10];
  const float* Whh_b = (const float*)d_in[11];
  const float* bih_b = (const float*)d_in[12];
  const float* bhh_b = (const float*)d_in[13];
  const float* Wtag  = (const float*)d_in[14];
  const float* btag  = (const float*)d_in[15];
  const float* trans = (const float*)d_in[16];

  float* ws   = (float*)d_ws;
  unsigned short* x16  = (unsigned short*)ws;
  unsigned short* w16n = (unsigned short*)(ws + 2490368);
  float* bias = ws + 3112960;
  unsigned int* W16u = (unsigned int*)(ws + 3115008);
  uint4* W16  = (uint4*)W16u;
  float* gin  = ws + 3639296;
  float* hseq = ws + 20416512;
  float* emit = ws + 24610816;
  float* nll  = ws + 24922112;
  float* out  = (float*)d_out;

  // allow >64KB dynamic LDS for k_lstm (one-time; host-side attribute set)
  static bool s_attr = false;
  if (!s_attr){
    (void)hipFuncSetAttribute((const void*)k_lstm,
                              hipFuncAttributeMaxDynamicSharedMemorySize,
                              K_LSTM_LDS_BYTES);
    s_attr = true;
  }

  hipLaunchKernelGGL(k_prep, dim3(EMBED_BLKS + W16N_BLKS + WHH_BLKS), dim3(256), 0, stream,
                     wi, msk, emb, Wih_f, Wih_b, bih_f, bhh_f, bih_b, bhh_b,
                     Whh_f, Whh_b, (unsigned int*)x16, (unsigned int*)w16n, bias, W16u);
  hipLaunchKernelGGL(k_gemm,   dim3(32,128),  dim3(256),  0, stream, x16, w16n, bias, gin);
  hipLaunchKernelGGL(k_lstm,   dim3(64),      dim3(512),  K_LSTM_LDS_BYTES, stream,
                     gin, W16, hseq);
  hipLaunchKernelGGL(k_emit,   dim3(608),     dim3(256),  0, stream, hseq, Wtag, btag, emit);
  hipLaunchKernelGGL(k_crfvit, dim3(64),      dim3(64),   0, stream, emit, msk, lab, trans,
                     nll, out);
  hipLaunchKernelGGL(k_final,  dim3(1),       dim3(64),   0, stream, nll, out);
}

// Round 5
// 758.998 us; speedup vs baseline: 2.8108x; 1.1338x over previous
//
#include <hip/hip_runtime.h>
#include <hip/hip_fp16.h>
#include <math.h>

// Problem constants (fixed shapes from the reference)
#define BB 32
#define SS 256
#define EE 300
#define KP 320          // E padded to multiple of 32 (MFMA K)
#define HH 256
#define TT 19           // NUM_TAGS + START + STOP
#define START_TAG 17
#define STOP_TAG 18
#define BS 8192         // B*S
#define GIN_PER_DIR (8192*1024)

// k_lstm weight residency split (per thread, of 16 u-chunks x 4 gates):
//   RCH u-chunks in registers (volatile-asm pinned), 16-RCH u-chunks in LDS.
#define RCH 12                       // 48 uint4 = 192 dwords persistent (VGPR+AGPR)
#define LDS_WCHUNK (16 - RCH)        // 4 chunks -> 16 slots x 512 uint4 = 128 KB
#define K_LSTM_LDS_BYTES ((8192 + 32 + 256) * 16)   // wlds + hsq + glh = 135680 B

// merged prep kernel block ranges
#define EMBED_BLKS 1280
#define W16N_BLKS  329
#define WHH_BLKS   1024

typedef _Float16 half8 __attribute__((ext_vector_type(8)));
typedef float    f32x4 __attribute__((ext_vector_type(4)));

// ---- fast transcendentals (v_exp_f32 / v_rcp_f32 based) ----
__device__ __forceinline__ float fexp(float x){
#if defined(__has_builtin) && __has_builtin(__builtin_amdgcn_exp2f)
  return __builtin_amdgcn_exp2f(x * 1.4426950408889634f);
#else
  return expf(x);
#endif
}
__device__ __forceinline__ float frcp(float x){
#if defined(__has_builtin) && __has_builtin(__builtin_amdgcn_rcpf)
  return __builtin_amdgcn_rcpf(x);
#else
  return 1.0f/x;
#endif
}
__device__ __forceinline__ float sigm(float x){ return frcp(1.0f + fexp(-x)); }
__device__ __forceinline__ float ftanh(float x){
  x = fminf(fmaxf(x, -20.f), 20.f);               // keep e finite; tanh saturated anyway
  float e = fexp(2.0f*x);
  return (e - 1.0f) * frcp(e + 1.0f);
}

#ifdef __has_builtin
#if __has_builtin(__builtin_amdgcn_fdot2)
#define HAVE_FDOT2 1
#endif
#endif

// v_dot2_f32_f16: acc += lo(w)*lo(h) + hi(w)*hi(h), f32 accumulate
__device__ __forceinline__ float dot2(unsigned int w, unsigned int h, float acc){
#ifdef HAVE_FDOT2
  typedef _Float16 h2_t __attribute__((ext_vector_type(2)));
  return __builtin_amdgcn_fdot2(__builtin_bit_cast(h2_t, w),
                                __builtin_bit_cast(h2_t, h), acc, false);
#else
  float r;
  asm("v_dot2_f32_f16 %0, %1, %2, %3" : "=v"(r) : "v"(w), "v"(h), "v"(acc));
  return r;
#endif
}

// volatile-asm 16B load: cannot be duplicated/rematerialized by the compiler,
// so the result MUST stay register-resident across the step loop.
__device__ __forceinline__ uint4 vload_u4(const uint4* p){
  uint4 r;
  asm volatile("global_load_dwordx4 %0, %1, off"
               : "=&v"(r) : "v"(p) : "memory");
  return r;
}

// RNE pack of two f32 values into a half2 dword
__device__ __forceinline__ unsigned int pack_h2(float a, float b){
  unsigned int lo = __half_as_ushort(__float2half(a));
  unsigned int hi = __half_as_ushort(__float2half(b));
  return (hi << 16) | lo;
}

// 16 dot2 = 32 MACs: one k-chunk of 8 (uint4 hu = 8 packed fp16 h) x 4 gates
__device__ __forceinline__ void mac4(uint4 w0, uint4 w1, uint4 w2, uint4 w3, uint4 hu,
                                     float& ai, float& af, float& ag, float& ao){
  ai = dot2(w0.x, hu.x, ai); ai = dot2(w0.y, hu.y, ai); ai = dot2(w0.z, hu.z, ai); ai = dot2(w0.w, hu.w, ai);
  af = dot2(w1.x, hu.x, af); af = dot2(w1.y, hu.y, af); af = dot2(w1.z, hu.z, af); af = dot2(w1.w, hu.w, af);
  ag = dot2(w2.x, hu.x, ag); ag = dot2(w2.y, hu.y, ag); ag = dot2(w2.z, hu.z, ag); ag = dot2(w2.w, hu.w, ag);
  ao = dot2(w3.x, hu.x, ao); ao = dot2(w3.y, hu.y, ao); ao = dot2(w3.z, hu.z, ao); ao = dot2(w3.w, hu.w, ao);
}

// ---------------- ws layout (float offsets) ----------------
// x16k  : [40][8192][8] fp16 k-chunk-major   off 0        size 1310720 (floats used)
// W16k  : [40][2048][8] fp16 k-chunk-major   off 2490368  size 327680  (rows permuted n=(j*4+g)+1024*dir)
// bias2 : [2048]               off 3112960    size 2048
// W16   : fp16 Whh packed      off 3115008    size 262144 floats used (1 MB)
// gin   : [2][BS][1024]        off 3639296    size 16777216 (preacts, interleaved row j*4+g)
// hseq  : [BS][512]            off 20416512   size 4194304
// emit  : [BS][19]             off 24610816   size 155648
// nll   : [32]                 off 24922112

// -------- merged prep: embed-gather+fp16 | Wih fp16 panel + bias | Whh fp16 pack --------
__global__ void k_prep(const int* __restrict__ wi, const int* __restrict__ msk,
                       const float* __restrict__ emb,
                       const float* __restrict__ Wih_f, const float* __restrict__ Wih_b,
                       const float* __restrict__ bih_f, const float* __restrict__ bhh_f,
                       const float* __restrict__ bih_b, const float* __restrict__ bhh_b,
                       const float* __restrict__ Whh_f, const float* __restrict__ Whh_b,
                       unsigned int* __restrict__ x16, unsigned int* __restrict__ w16n,
                       float* __restrict__ bias, unsigned int* __restrict__ whh16){
  unsigned bx = blockIdx.x;
  if (bx < EMBED_BLKS){
    // ---- embed gather + mask -> fp16, k-chunk-major x16k[q][row] ----
    int id = bx*256 + threadIdx.x;               // id = q*8192 + row, q=0..39
    if (id >= BS*40) return;
    int q = id >> 13, row = id & 8191;
    float m = (float)msk[row];
    const float4* e4 = (const float4*)emb + (size_t)wi[row]*75 + q*2;
    float4 v0 = make_float4(0.f,0.f,0.f,0.f), v1 = v0;
    if (q <= 37) v0 = e4[0];                     // k = q*8 .. q*8+3  (<300)
    if (q <= 36) v1 = e4[1];                     // k = q*8+4 .. +7
    uint4 o;
    o.x = pack_h2(v0.x*m, v0.y*m); o.y = pack_h2(v0.z*m, v0.w*m);
    o.z = pack_h2(v1.x*m, v1.y*m); o.w = pack_h2(v1.z*m, v1.w*m);
    ((uint4*)x16)[id] = o;                       // coalesced: id enumerates [q][row]
  } else if (bx < EMBED_BLKS + W16N_BLKS){
    // ---- Wih -> fp16 k-chunk-major panel [40][2048][8], rows n=(j*4+g)+1024*dir; + bias ----
    int id = (bx - EMBED_BLKS)*256 + threadIdx.x;
    if (id < 2048*40){
      int kc = id >> 11, n = id & 2047;
      int dd = n >> 10, r = n & 1023, j = r >> 2, g = r & 3;
      const float4* W4 = (const float4*)(dd ? Wih_b : Wih_f) + (size_t)(g*256 + j)*75 + kc*2;
      float4 v0 = make_float4(0.f,0.f,0.f,0.f), v1 = v0;
      if (kc <= 37) v0 = W4[0];
      if (kc <= 36) v1 = W4[1];
      uint4 o;
      o.x = pack_h2(v0.x, v0.y); o.y = pack_h2(v0.z, v0.w);
      o.z = pack_h2(v1.x, v1.y); o.w = pack_h2(v1.z, v1.w);
      ((uint4*)w16n)[id] = o;
    } else {
      int n = id - 2048*40;
      if (n < 2048){
        int dd = n >> 10, r = n & 1023, j = r >> 2, g = r & 3;
        int orow = g*256 + j;
        bias[n] = dd ? (bih_b[orow] + bhh_b[orow]) : (bih_f[orow] + bhh_f[orow]);
      }
    }
  } else {
    // ---- pack Whh to fp16 (k_lstm layout) ----
    int id = (bx - EMBED_BLKS - W16N_BLKS)*256 + threadIdx.x;   // 262144 uints
    int j   = id & 3;
    int u4  = id >> 2;                             // uint4 index
    int tid = u4 & 511;
    int q   = (u4 >> 9) & 63;
    int d   = u4 >> 15;
    int kpart = tid >> 8, urow = tid & 255;
    int u = q >> 2, g = q & 3;
    int k = kpart*128 + u*8 + j*2;
    const float* W = d ? Whh_b : Whh_f;
    float w0 = W[(size_t)(g*256 + urow)*256 + k];
    float w1 = W[(size_t)(g*256 + urow)*256 + k + 1];
    whh16[id] = pack_h2(w0, w1);
  }
}

// -------- input-gate GEMM via MFMA f16, k-chunk-major operands --------
// 64x64 block tile, 4 waves; wave w owns n-strip [bx*64+w*16,+16), M-rep 4.
// A load: x16k[(kt*4+kg)*8192 + m] -> 16 lanes x 16B contiguous (256B segs).
// B load: w16k[(kt*4+kg)*2048 + n] -> same. C staged through LDS f32 tile so
// global writes are 256B row segments with fused bias.
__global__ __launch_bounds__(256) void k_gemm(const uint4* __restrict__ x16k,
      const uint4* __restrict__ w16k, const float* __restrict__ bias,
      float* __restrict__ gin){
  __shared__ float Cs[64][68];
  int tid = threadIdx.x;
  int l = tid & 63, w = tid >> 6;
  int lm = l & 15, kg = l >> 4;
  int m0 = blockIdx.y * 64;
  int n0 = blockIdx.x * 64;
  int nw = n0 + w*16;
  const uint4* A  = x16k + (size_t)kg*8192 + m0 + lm;
  const uint4* Bp = w16k + (size_t)kg*2048 + nw + lm;
  f32x4 acc0 = {0.f,0.f,0.f,0.f}, acc1 = acc0, acc2 = acc0, acc3 = acc0;
  #pragma unroll
  for (int kt = 0; kt < 10; ++kt){
    half8 b  = __builtin_bit_cast(half8, Bp[(size_t)kt*8192]);          // 4*2048
    half8 a0 = __builtin_bit_cast(half8, A[(size_t)kt*32768      ]);    // 4*8192
    half8 a1 = __builtin_bit_cast(half8, A[(size_t)kt*32768 + 16 ]);
    half8 a2 = __builtin_bit_cast(half8, A[(size_t)kt*32768 + 32 ]);
    half8 a3 = __builtin_bit_cast(half8, A[(size_t)kt*32768 + 48 ]);
    acc0 = __builtin_amdgcn_mfma_f32_16x16x32_f16(a0, b, acc0, 0, 0, 0);
    acc1 = __builtin_amdgcn_mfma_f32_16x16x32_f16(a1, b, acc1, 0, 0, 0);
    acc2 = __builtin_amdgcn_mfma_f32_16x16x32_f16(a2, b, acc2, 0, 0, 0);
    acc3 = __builtin_amdgcn_mfma_f32_16x16x32_f16(a3, b, acc3, 0, 0, 0);
  }
  // C frag (verified m89/m91): col = lane&15 (n), row = (lane>>4)*4 + reg (m)
  int cl = w*16 + lm;
  #pragma unroll
  for (int reg = 0; reg < 4; ++reg){
    Cs[kg*4 + reg     ][cl] = acc0[reg];
    Cs[kg*4 + reg + 16][cl] = acc1[reg];
    Cs[kg*4 + reg + 32][cl] = acc2[reg];
    Cs[kg*4 + reg + 48][cl] = acc3[reg];
  }
  __syncthreads();
  int mloc = tid >> 4, c4 = (tid & 15)*4;
  int n = n0 + c4;                       // block n-range stays within one dir
  int dd = n >> 10, r = n & 1023;
  float4 bn = *(const float4*)&bias[n];
  float* go = gin + (size_t)dd*GIN_PER_DIR + r;
  #pragma unroll
  for (int rep = 0; rep < 4; ++rep){
    int ml = rep*16 + mloc;
    float4 v = *(const float4*)&Cs[ml][c4];
    v.x += bn.x; v.y += bn.y; v.z += bn.z; v.w += bn.w;
    *(float4*)&go[(size_t)(m0 + ml)*1024] = v;
  }
}

// -------- BiLSTM recurrence: fully-resident weights (VGPR/AGPR + LDS), zero L2 stream --------
__global__ __launch_bounds__(512, 2) void k_lstm(const float* __restrict__ gin,
                 const uint4* __restrict__ W16, float* __restrict__ hseq){
  extern __shared__ uint4 smem[];
  uint4*  wlds = smem;                       // [16 slots][512] = 8192 uint4 (128 KB)
  uint4*  hsq  = smem + 8192;                // 32 uint4: h packed fp16 (512 B)
  float4* glh  = (float4*)(smem + 8224);     // 256 float4: kpart=1 partials (4 KB)

  int tid = threadIdx.x;
  int b = blockIdx.x & 31, d = blockIdx.x >> 5;
  int kpart = tid >> 8;                              // 0..1
  const uint4* wq = W16 + (size_t)d*64*512 + tid;    // + q*512 per q
  const float* gb = gin + (size_t)d*GIN_PER_DIR + (size_t)b*SS*1024;

  // ---- stage LDS weight chunks (u = RCH..15 -> q = 48..63), once ----
  #pragma unroll
  for (int q = 4*RCH; q < 64; ++q)
    wlds[(q - 4*RCH)*512 + tid] = wq[(size_t)q*512];

  if (tid < 32) hsq[tid] = make_uint4(0u,0u,0u,0u);

  // ---- pin register weight chunks (q = 0..47) via volatile asm ----
  uint4 wr[4*RCH];
  #pragma unroll
  for (int q = 0; q < 4*RCH; ++q) wr[q] = vload_u4(wq + (size_t)q*512);
  asm volatile("s_waitcnt vmcnt(0)" ::: "memory");
  __builtin_amdgcn_sched_barrier(0);

  float c = 0.f;
  __syncthreads();

  const uint4* wl = wlds + tid;
  for (int s = 0; s < SS; ++s){
    int t = d ? (SS-1-s) : s;
    float4 gv = make_float4(0.f,0.f,0.f,0.f);
    if (tid < 256) gv = ((const float4*)(gb + (size_t)t*1024))[tid];  // prefetch preacts

    float ai = 0.f, af = 0.f, ag = 0.f, ao = 0.f;
    // register-resident chunks
    #pragma unroll
    for (int u = 0; u < RCH; ++u){
      uint4 hu = hsq[kpart*16 + u];                  // wave-uniform LDS broadcast
      mac4(wr[u*4+0], wr[u*4+1], wr[u*4+2], wr[u*4+3], hu, ai, af, ag, ao);
    }
    // LDS-resident chunks
    #pragma unroll
    for (int uu = 0; uu < LDS_WCHUNK; ++uu){
      uint4 hu = hsq[kpart*16 + RCH + uu];
      uint4 w0 = wl[(uu*4+0)*512];
      uint4 w1 = wl[(uu*4+1)*512];
      uint4 w2 = wl[(uu*4+2)*512];
      uint4 w3 = wl[(uu*4+3)*512];
      mac4(w0, w1, w2, w3, hu, ai, af, ag, ao);
    }
    if (kpart) glh[tid & 255] = make_float4(ai, af, ag, ao);
    __syncthreads();
    if (tid < 256){
      float4 p1 = glh[tid];
      float iv = sigm (ai + p1.x + gv.x);
      float fv = sigm (af + p1.y + gv.y);
      float gg = ftanh(ag + p1.z + gv.z);
      float ov = sigm (ao + p1.w + gv.w);
      c = fv*c + iv*gg;
      float hv = ov*ftanh(c);
      hseq[((size_t)(b*SS + t))*512 + d*256 + tid] = hv;
      float hp = __shfl_xor(hv, 1);                  // partner h within wave
      if (!(tid & 1))
        ((unsigned int*)hsq)[tid >> 1] = pack_h2(hv, hp);
    }
    __syncthreads();
  }
}

// -------- tag logits: emit[row][t] = hseq[row] . W_tag[t] + b_tag[t] --------
// Wtag staged in LDS ([19][516] pad to spread banks) -> global loads are hseq only.
__global__ __launch_bounds__(256) void k_emit(const float* __restrict__ hseq,
                       const float* __restrict__ Wtag,
                       const float* __restrict__ btag, float* __restrict__ emit){
  __shared__ float wt[19][516];
  __shared__ float bt[19];
  int tid = threadIdx.x;
  for (int i = tid; i < 19*512; i += 256) wt[i / 512][i & 511] = Wtag[i];
  if (tid < 19) bt[tid] = btag[tid];
  __syncthreads();
  int id = blockIdx.x*256 + tid;
  if (id >= BS*TT) return;
  int row = id / TT, tg = id - row*TT;
  const float4* hp = (const float4*)(hseq + (size_t)row*512);
  const float*  wp = &wt[tg][0];
  float acc = bt[tg];
  #pragma unroll 8
  for (int k = 0; k < 128; ++k){
    float4 h = hp[k];
    const float4 w = *(const float4*)&wp[k*4];
    acc += h.x*w.x + h.y*w.y + h.z*w.z + h.w*w.w;
  }
  emit[id] = acc;
}

// -------- fused CRF NLL + Viterbi, v2: all per-batch state LDS-resident --------
// blocks 0..31 CRF(b), 32..63 Viterbi(b-32). emit row (19.5 KB), mask, labels and
// Viterbi back-pointers (ushort) staged in LDS before the serial t-loop, so the
// 255-step recurrences and the backtrack chain never touch global memory.
__global__ __launch_bounds__(64) void k_crfvit(const float* __restrict__ emit,
                         const int* __restrict__ msk,
                         const int* __restrict__ lab, const float* __restrict__ trans,
                         float* __restrict__ nll, float* __restrict__ out){
  int tid = threadIdx.x;
  __shared__ float tr[361];
  __shared__ float eb[SS*TT];          // 19456 B: this batch's emit row
  __shared__ int   ml[SS];             // mask
  __shared__ int   ll[SS];             // labels (CRF only)
  __shared__ unsigned short pv[SS*TT]; // viterbi back-pointers (9728 B)
  __shared__ float al[TT];
  __shared__ int   tg[SS];

  int b = blockIdx.x & 31;
  const float* ebg = emit + (size_t)b*SS*TT;
  for (int i = tid; i < 361; i += 64) tr[i] = trans[i];
  for (int i = tid; i < SS*TT; i += 64) eb[i] = ebg[i];
  for (int i = tid; i < SS; i += 64) ml[i] = msk[b*SS + i];

  if (blockIdx.x < 32){
    // ---- CRF forward (NLL) ----
    for (int i = tid; i < SS; i += 64) ll[i] = lab[b*SS + i];
    __syncthreads();
    float gp = 0.f; int ln = 0;
    for (int t = tid; t < SS; t += 64){
      int m = ml[t];
      ln += m;
      if (m){
        int l = ll[t];
        int p = t ? ll[t-1] : START_TAG;
        gp += tr[p*19 + l] + eb[t*19 + l];
      }
    }
    for (int off = 32; off; off >>= 1){ gp += __shfl_down(gp, off); ln += __shfl_down(ln, off); }
    float gold = 0.f;
    if (tid == 0){
      int lt = ll[ln - 1];
      gold = gp + tr[lt*19 + STOP_TAG];
    }
    if (tid < 19) al[tid] = eb[tid] + tr[START_TAG*19 + tid];
    __syncthreads();
    for (int t = 1; t < SS; ++t){
      float nv = 0.f;
      if (tid < 19){
        float mx = -1e30f;
        #pragma unroll
        for (int p = 0; p < 19; ++p){ float v = al[p] + tr[p*19 + tid]; mx = fmaxf(mx, v); }
        float sum = 0.f;
        #pragma unroll
        for (int p = 0; p < 19; ++p) sum += fexp(al[p] + tr[p*19 + tid] - mx);
        nv = mx + logf(sum) + eb[t*19 + tid];
      }
      __syncthreads();
      if (tid < 19 && ml[t]) al[tid] = nv;
      __syncthreads();
    }
    if (tid == 0){
      float mx = -1e30f;
      for (int c2 = 0; c2 < 19; ++c2) mx = fmaxf(mx, al[c2] + tr[c2*19 + STOP_TAG]);
      float sum = 0.f;
      for (int c2 = 0; c2 < 19; ++c2) sum += fexp(al[c2] + tr[c2*19 + STOP_TAG] - mx);
      nll[b] = (mx + logf(sum)) - gold;
    }
  } else {
    // ---- Viterbi decode (LDS back-pointers + LDS backtrack) ----
    if (tid < 19) al[tid] = eb[tid] + tr[START_TAG*19 + tid];   // al doubles as delta
    __syncthreads();
    for (int t = 1; t < SS; ++t){
      int m = ml[t];
      float best = -1e30f; int bp = 0;
      if (tid < 19){
        #pragma unroll
        for (int p = 0; p < 19; ++p){
          float v = al[p] + tr[p*19 + tid];
          if (v > best){ best = v; bp = p; }       // strict > == first-max (jnp.argmax)
        }
      }
      __syncthreads();
      if (tid < 19){
        if (m){ al[tid] = best + eb[t*19 + tid]; pv[t*19 + tid] = (unsigned short)bp; }
        else  { pv[t*19 + tid] = (unsigned short)tid; }   // identity pass-through
      }
      __syncthreads();
    }
    if (tid == 0){
      float bv = -1e30f; int bl = 0;
      for (int c2 = 0; c2 < 19; ++c2){
        float v = al[c2] + tr[c2*19 + STOP_TAG];
        if (v > bv){ bv = v; bl = c2; }
      }
      tg[SS-1] = bl;
      for (int t = SS-1; t > 0; --t) tg[t-1] = pv[t*19 + tg[t]];
    }
    __syncthreads();
    for (int t = tid; t < SS; t += 64)
      out[1 + b*SS + t] = (float)(tg[t] * ml[t]);
  }
}

// -------- final loss reduce: d_out[0] = sum(nll)/B --------
__global__ void k_final(const float* __restrict__ nll, float* __restrict__ out){
  int tid = threadIdx.x;
  float v = (tid < 32) ? nll[tid] : 0.f;
  for (int off = 32; off; off >>= 1) v += __shfl_down(v, off);
  if (tid == 0) out[0] = v * (1.0f/32.0f);
}

extern "C" void kernel_launch(void* const* d_in, const int* in_sizes, int n_in,
                              void* d_out, int out_size, void* d_ws, size_t ws_size,
                              hipStream_t stream){
  const int*   wi    = (const int*)d_in[0];
  const int*   msk   = (const int*)d_in[1];
  const int*   lab   = (const int*)d_in[2];
  // d_in[3] labels_token, d_in[4] data_type: unused (data_type==1 branch)
  const float* emb   = (const float*)d_in[5];
  const float* Wih_f = (const float*)d_in[6];
  const float* Whh_f = (const float*)d_in[7];
  const float* bih_f = (const float*)d_in[8];
  const float* bhh_f = (const float*)d_in[9];
  const float* Wih_b = (const float*)d_in[10];
  const float* Whh_b = (const float*)d_in[11];
  const float* bih_b = (const float*)d_in[12];
  const float* bhh_b = (const float*)d_in[13];
  const float* Wtag  = (const float*)d_in[14];
  const float* btag  = (const float*)d_in[15];
  const float* trans = (const float*)d_in[16];

  float* ws   = (float*)d_ws;
  unsigned short* x16  = (unsigned short*)ws;
  unsigned short* w16n = (unsigned short*)(ws + 2490368);
  float* bias = ws + 3112960;
  unsigned int* W16u = (unsigned int*)(ws + 3115008);
  uint4* W16  = (uint4*)W16u;
  float* gin  = ws + 3639296;
  float* hseq = ws + 20416512;
  float* emit = ws + 24610816;
  float* nll  = ws + 24922112;
  float* out  = (float*)d_out;

  // allow >64KB dynamic LDS for k_lstm (one-time; host-side attribute set)
  static bool s_attr = false;
  if (!s_attr){
    (void)hipFuncSetAttribute((const void*)k_lstm,
                              hipFuncAttributeMaxDynamicSharedMemorySize,
                              K_LSTM_LDS_BYTES);
    s_attr = true;
  }

  hipLaunchKernelGGL(k_prep, dim3(EMBED_BLKS + W16N_BLKS + WHH_BLKS), dim3(256), 0, stream,
                     wi, msk, emb, Wih_f, Wih_b, bih_f, bhh_f, bih_b, bhh_b,
                     Whh_f, Whh_b, (unsigned int*)x16, (unsigned int*)w16n, bias, W16u);
  hipLaunchKernelGGL(k_gemm,   dim3(32,128),  dim3(256),  0, stream,
                     (const uint4*)x16, (const uint4*)w16n, bias, gin);
  hipLaunchKernelGGL(k_lstm,   dim3(64),      dim3(512),  K_LSTM_LDS_BYTES, stream,
                     gin, W16, hseq);
  hipLaunchKernelGGL(k_emit,   dim3(608),     dim3(256),  0, stream, hseq, Wtag, btag, emit);
  hipLaunchKernelGGL(k_crfvit, dim3(64),      dim3(64),   0, stream, emit, msk, lab, trans,
                     nll, out);
  hipLaunchKernelGGL(k_final,  dim3(1),       dim3(64),   0, stream, nll, out);
}